// Round 1
// baseline (9300.964 us; speedup 1.0000x reference)
//
#include <hip/hip_runtime.h>
#include <math.h>

#define B 256
#define KW 7

// ---------------------------------------------------------------------------
// helpers
// ---------------------------------------------------------------------------
__device__ __forceinline__ void block_reduce2(float& s, float& s2, float* lds) {
    // reduce across 256 threads (4 waves of 64); result valid in thread 0
    for (int off = 32; off > 0; off >>= 1) {
        s  += __shfl_down(s,  off, 64);
        s2 += __shfl_down(s2, off, 64);
    }
    int wave = threadIdx.x >> 6;
    int lane = threadIdx.x & 63;
    if (lane == 0) { lds[wave * 2] = s; lds[wave * 2 + 1] = s2; }
    __syncthreads();
    if (threadIdx.x == 0) {
        s  = lds[0] + lds[2] + lds[4] + lds[6];
        s2 = lds[1] + lds[3] + lds[5] + lds[7];
    }
}

// ---------------------------------------------------------------------------
// x (B, 4, 2048) -> A0 [t][n][c][b]   (t,c in 0..1, n 0..2047, b 0..255)
// ---------------------------------------------------------------------------
__global__ __launch_bounds__(256) void k_transpose(const float* __restrict__ x,
                                                   float* __restrict__ A0) {
    int idx = blockIdx.x * 256 + threadIdx.x;   // total 2*2048*2*256
    int b = idx & 255;
    int r = idx >> 8;
    int c = r & 1;  r >>= 1;
    int n = r & 2047;
    int t = r >> 11;
    A0[idx] = x[((size_t)b * 4 + (t * 2 + c)) * 2048 + n];
}

// ---------------------------------------------------------------------------
// fused indexed-conv + indexed-maxpool (+ bias), input BN+relu applied on the
// fly via per-(t,c_in) scale/shift.  act [2][N_in][C_in][B] -> out [2][N_out][C_out][B]
// One block: one (t, n_out) column x 32 c_out x all 256 b.
// ---------------------------------------------------------------------------
__global__ __launch_bounds__(256) void k_convpool(
    const float* __restrict__ act,
    float* __restrict__ out,
    const float* __restrict__ w,        // [C_out][C_in][7]
    const float* __restrict__ bias,     // [C_out]
    const int* __restrict__ idx_conv,   // [7][N_in]
    const int* __restrict__ idx_pool,   // [7][N_out]
    const float* __restrict__ scale_in, // [2][C_in]
    const float* __restrict__ shift_in, // [2][C_in]
    int C_in, int C_out, int N_in, int N_out, int apply_in)
{
    const int Kt  = C_in * KW;
    const int nco = C_out >> 5;          // tiles of 32 c_out
    int bid   = blockIdx.x;
    int cot   = bid % nco;
    int colid = bid / nco;
    int t     = colid / N_out;
    int np    = colid - t * N_out;
    int co0   = cot << 5;

    __shared__ float lds_g[32 * 256];
    __shared__ float lds_w[32 * 33];     // [kk][co] padded (+1 col)
    __shared__ int   lds_idx[KW];

    int tid = threadIdx.x;
    int cog = tid >> 6;                  // 0..3  (wave-uniform)
    int bl  = tid & 63;

    float pmax[8][4];
    #pragma unroll
    for (int i = 0; i < 8; i++)
        #pragma unroll
        for (int j = 0; j < 4; j++) pmax[i][j] = -INFINITY;

    const float* actT = act + (size_t)t * N_in * C_in * B;
    const float* sc   = scale_in + t * C_in;
    const float* sh   = shift_in + t * C_in;

    for (int kp = 0; kp < KW; kp++) {
        int nc = idx_pool[kp * N_out + np];          // conv column to compute
        if (tid < KW) lds_idx[tid] = idx_conv[tid * N_in + nc];

        float acc[8][4];
        #pragma unroll
        for (int i = 0; i < 8; i++)
            #pragma unroll
            for (int j = 0; j < 4; j++) acc[i][j] = 0.f;

        for (int kk0 = 0; kk0 < Kt; kk0 += 32) {
            int rows = min(32, Kt - kk0);
            __syncthreads();   // protects lds_* reuse, publishes lds_idx
            // weight chunk: 32 c_out x rows kk  (coalesced global, padded LDS)
            for (int e = tid; e < 32 * rows; e += 256) {
                int kk = e % rows;
                int co = e / rows;
                lds_w[kk * 33 + co] = w[(size_t)(co0 + co) * Kt + kk0 + kk];
            }
            // gathered input chunk: rows x 256 b  (each row contiguous)
            for (int r = 0; r < rows; r++) {
                int kkg = kk0 + r;
                int ci  = kkg / KW;
                int k   = kkg - ci * KW;
                int col = lds_idx[k];
                float v = actT[((size_t)col * C_in + ci) * B + tid];
                if (apply_in) v = fmaxf(fmaf(v, sc[ci], sh[ci]), 0.f);
                lds_g[r * 256 + tid] = v;
            }
            __syncthreads();
            for (int kk = 0; kk < rows; kk++) {
                float g0 = lds_g[kk * 256 + bl];
                float g1 = lds_g[kk * 256 + bl + 64];
                float g2 = lds_g[kk * 256 + bl + 128];
                float g3 = lds_g[kk * 256 + bl + 192];
                const float* wr = lds_w + kk * 33 + cog * 8;  // broadcast reads
                #pragma unroll
                for (int i = 0; i < 8; i++) {
                    float wv = wr[i];
                    acc[i][0] = fmaf(wv, g0, acc[i][0]);
                    acc[i][1] = fmaf(wv, g1, acc[i][1]);
                    acc[i][2] = fmaf(wv, g2, acc[i][2]);
                    acc[i][3] = fmaf(wv, g3, acc[i][3]);
                }
            }
        }
        #pragma unroll
        for (int i = 0; i < 8; i++)
            #pragma unroll
            for (int j = 0; j < 4; j++) pmax[i][j] = fmaxf(pmax[i][j], acc[i][j]);
    }

    float* outp = out + (((size_t)t * N_out + np) * C_out + co0) * B;
    #pragma unroll
    for (int i = 0; i < 8; i++) {
        int co = cog * 8 + i;
        float bv = bias[co0 + co];
        #pragma unroll
        for (int j = 0; j < 4; j++)
            outp[(size_t)co * B + bl + 64 * j] = pmax[i][j] + bv;
    }
}

// ---------------------------------------------------------------------------
// per-(t,c) BN stats over (n,b) -> scale/shift  (scale=istd*gamma, shift=beta-m*scale)
// ---------------------------------------------------------------------------
__global__ __launch_bounds__(256) void k_stats(
    const float* __restrict__ P,      // [2][N][C][B]
    const float* __restrict__ gamma,
    const float* __restrict__ beta,
    float* __restrict__ scale,        // [2][C]
    float* __restrict__ shift,
    int C, int N)
{
    int bid = blockIdx.x;             // t*C + c
    int t = bid / C, c = bid - t * C;
    const float* base = P + ((size_t)t * N * C + c) * B;
    float s = 0.f, s2 = 0.f;
    for (int n = 0; n < N; n++) {
        float v = base[(size_t)n * C * B + threadIdx.x];
        s += v; s2 += v * v;
    }
    __shared__ float lds[8];
    block_reduce2(s, s2, lds);
    if (threadIdx.x == 0) {
        float cnt  = (float)N * (float)B;
        float m    = s / cnt;
        float var  = s2 / cnt - m * m;
        float istd = rsqrtf(var + 1e-5f);
        float g    = gamma[c];
        scale[bid] = istd * g;
        shift[bid] = beta[c] - m * istd * g;
    }
}

// ---------------------------------------------------------------------------
// z[f][b] = 0.5*(relu(bn(P4[0])) + relu(bn(P4[1]))),  f = c*8 + n
// ---------------------------------------------------------------------------
__global__ __launch_bounds__(256) void k_zbuild(
    const float* __restrict__ P4,     // [2][8][512][B]
    const float* __restrict__ scale4, // [2][512]
    const float* __restrict__ shift4,
    float* __restrict__ z)            // [4096][B]
{
    int f = blockIdx.x;
    int c = f >> 3, n = f & 7;
    int b = threadIdx.x;
    float v0 = P4[(((size_t)0 * 8 + n) * 512 + c) * B + b];
    float v1 = P4[(((size_t)1 * 8 + n) * 512 + c) * B + b];
    v0 = fmaxf(fmaf(v0, scale4[c],       shift4[c]),       0.f);
    v1 = fmaxf(fmaf(v1, scale4[512 + c], shift4[512 + c]), 0.f);
    z[(size_t)f * B + b] = 0.5f * (v0 + v1);
}

// ---------------------------------------------------------------------------
// o1[h][b] = sum_f w1[h][f] * z[f][b] + b1[h]    (M=2048, N=256, K=4096)
// block: 16 h x 256 b
// ---------------------------------------------------------------------------
__global__ __launch_bounds__(256) void k_lin1(
    const float* __restrict__ z,      // [4096][256]
    const float* __restrict__ w1,     // [2048][4096]
    const float* __restrict__ b1,
    float* __restrict__ o1)           // [2048][256]
{
    __shared__ float lds_g[32 * 256];
    __shared__ float lds_w[32 * 17];  // [kk][h] padded
    int tid = threadIdx.x;
    int h0  = blockIdx.x * 16;
    int hg  = tid >> 6, bl = tid & 63;
    float acc[4][4];
    #pragma unroll
    for (int i = 0; i < 4; i++)
        #pragma unroll
        for (int j = 0; j < 4; j++) acc[i][j] = 0.f;

    for (int f0 = 0; f0 < 4096; f0 += 32) {
        __syncthreads();
        for (int e = tid; e < 512; e += 256) {
            int kk = e & 31, h = e >> 5;
            lds_w[kk * 17 + h] = w1[(size_t)(h0 + h) * 4096 + f0 + kk];
        }
        for (int r = 0; r < 32; r++)
            lds_g[r * 256 + tid] = z[(size_t)(f0 + r) * B + tid];
        __syncthreads();
        for (int kk = 0; kk < 32; kk++) {
            float g0 = lds_g[kk * 256 + bl];
            float g1 = lds_g[kk * 256 + bl + 64];
            float g2 = lds_g[kk * 256 + bl + 128];
            float g3 = lds_g[kk * 256 + bl + 192];
            const float* wr = lds_w + kk * 17 + hg * 4;
            #pragma unroll
            for (int i = 0; i < 4; i++) {
                float wv = wr[i];
                acc[i][0] = fmaf(wv, g0, acc[i][0]);
                acc[i][1] = fmaf(wv, g1, acc[i][1]);
                acc[i][2] = fmaf(wv, g2, acc[i][2]);
                acc[i][3] = fmaf(wv, g3, acc[i][3]);
            }
        }
    }
    #pragma unroll
    for (int i = 0; i < 4; i++) {
        int h = h0 + hg * 4 + i;
        float bv = b1[h];
        #pragma unroll
        for (int j = 0; j < 4; j++)
            o1[(size_t)h * B + bl + 64 * j] = acc[i][j] + bv;
    }
}

// ---------------------------------------------------------------------------
// BN5 stats: per-h over batch
// ---------------------------------------------------------------------------
__global__ __launch_bounds__(256) void k_stats5(
    const float* __restrict__ o1,     // [2048][256]
    const float* __restrict__ gamma5,
    const float* __restrict__ beta5,
    float* __restrict__ scale5,
    float* __restrict__ shift5)
{
    int h = blockIdx.x;
    float v  = o1[(size_t)h * B + threadIdx.x];
    float s = v, s2 = v * v;
    __shared__ float lds[8];
    block_reduce2(s, s2, lds);
    if (threadIdx.x == 0) {
        float m    = s * (1.f / 256.f);
        float var  = s2 * (1.f / 256.f) - m * m;
        float istd = rsqrtf(var + 1e-5f);
        float g    = gamma5[h];
        scale5[h]  = istd * g;
        shift5[h]  = beta5[h] - m * istd * g;
    }
}

// ---------------------------------------------------------------------------
// final: relu(bn5(o1)) @ lin2_w.T + lin2_b, then log_softmax over first 2 cols
// one block per batch element
// ---------------------------------------------------------------------------
__global__ __launch_bounds__(256) void k_final(
    const float* __restrict__ o1,     // [2048][256]
    const float* __restrict__ scale5,
    const float* __restrict__ shift5,
    const float* __restrict__ w2,     // [3][2048]
    const float* __restrict__ b2,     // [3]
    float* __restrict__ out)          // [256][3]
{
    int b = blockIdx.x;
    int tid = threadIdx.x;
    float s0 = 0.f, s1 = 0.f, s2v = 0.f;
    for (int h = tid; h < 2048; h += 256) {
        float y = fmaxf(fmaf(o1[(size_t)h * B + b], scale5[h], shift5[h]), 0.f);
        s0  = fmaf(y, w2[h],        s0);
        s1  = fmaf(y, w2[2048 + h], s1);
        s2v = fmaf(y, w2[4096 + h], s2v);
    }
    for (int off = 32; off > 0; off >>= 1) {
        s0  += __shfl_down(s0,  off, 64);
        s1  += __shfl_down(s1,  off, 64);
        s2v += __shfl_down(s2v, off, 64);
    }
    __shared__ float lds[12];
    int wave = tid >> 6, lane = tid & 63;
    if (lane == 0) { lds[wave * 3] = s0; lds[wave * 3 + 1] = s1; lds[wave * 3 + 2] = s2v; }
    __syncthreads();
    if (tid == 0) {
        float o0 = lds[0] + lds[3] + lds[6] + lds[9]  + b2[0];
        float oa = lds[1] + lds[4] + lds[7] + lds[10] + b2[1];
        float ob = lds[2] + lds[5] + lds[8] + lds[11] + b2[2];
        float m   = fmaxf(o0, oa);
        float lse = m + logf(expf(o0 - m) + expf(oa - m));
        out[b * 3 + 0] = o0 - lse;
        out[b * 3 + 1] = oa - lse;
        out[b * 3 + 2] = ob;
    }
}

// ---------------------------------------------------------------------------
extern "C" void kernel_launch(void* const* d_in, const int* in_sizes, int n_in,
                              void* d_out, int out_size, void* d_ws, size_t ws_size,
                              hipStream_t stream) {
    (void)in_sizes; (void)n_in; (void)out_size; (void)ws_size;

    const float* x   = (const float*)d_in[0];
    const int*   ic1 = (const int*)d_in[1];
    const int*   ip1 = (const int*)d_in[2];
    const float* pW1 = (const float*)d_in[3];
    const float* pB1 = (const float*)d_in[4];
    const float* pG1 = (const float*)d_in[5];
    const float* pE1 = (const float*)d_in[6];
    const int*   ic2 = (const int*)d_in[7];
    const int*   ip2 = (const int*)d_in[8];
    const float* pW2 = (const float*)d_in[9];
    const float* pB2 = (const float*)d_in[10];
    const float* pG2 = (const float*)d_in[11];
    const float* pE2 = (const float*)d_in[12];
    const int*   ic3 = (const int*)d_in[13];
    const int*   ip3 = (const int*)d_in[14];
    const float* pW3 = (const float*)d_in[15];
    const float* pB3 = (const float*)d_in[16];
    const float* pG3 = (const float*)d_in[17];
    const float* pE3 = (const float*)d_in[18];
    const int*   ic4 = (const int*)d_in[19];
    const int*   ip4 = (const int*)d_in[20];
    const float* pW4 = (const float*)d_in[21];
    const float* pB4 = (const float*)d_in[22];
    const float* pG4 = (const float*)d_in[23];
    const float* pE4 = (const float*)d_in[24];
    const float* lw1 = (const float*)d_in[25];
    const float* lb1 = (const float*)d_in[26];
    const float* g5  = (const float*)d_in[27];
    const float* e5  = (const float*)d_in[28];
    const float* lw2 = (const float*)d_in[29];
    const float* lb2 = (const float*)d_in[30];

    float* ws = (float*)d_ws;
    size_t off = 0;
    float* A0 = ws + off; off += (size_t)2 * 2048 * 2 * B;     // 2,097,152
    float* P1 = ws + off; off += (size_t)2 * 512 * 64 * B;     // 16,777,216
    float* P2 = ws + off; off += (size_t)2 * 128 * 128 * B;    //  8,388,608
    float* P3 = ws + off; off += (size_t)2 * 32 * 256 * B;     //  4,194,304
    float* P4 = ws + off; off += (size_t)2 * 8 * 512 * B;      //  2,097,152
    float* z  = ws + off; off += (size_t)4096 * B;             //  1,048,576
    float* o1 = ws + off; off += (size_t)2048 * B;             //    524,288
    float* sc1 = ws + off; off += 2 * 64;
    float* sh1 = ws + off; off += 2 * 64;
    float* sc2 = ws + off; off += 2 * 128;
    float* sh2 = ws + off; off += 2 * 128;
    float* sc3 = ws + off; off += 2 * 256;
    float* sh3 = ws + off; off += 2 * 256;
    float* sc4 = ws + off; off += 2 * 512;
    float* sh4 = ws + off; off += 2 * 512;
    float* sc5 = ws + off; off += 2048;
    float* sh5 = ws + off; off += 2048;

    // input layout transform
    k_transpose<<<(2 * 2048 * 2 * B) / 256, 256, 0, stream>>>(x, A0);

    // layer 1: 2 -> 64, N 2048 -> 512 (no input BN)
    k_convpool<<<(64 / 32) * 2 * 512, 256, 0, stream>>>(A0, P1, pW1, pB1, ic1, ip1,
                                                        sc1, sh1, 2, 64, 2048, 512, 0);
    k_stats<<<2 * 64, 256, 0, stream>>>(P1, pG1, pE1, sc1, sh1, 64, 512);

    // layer 2: 64 -> 128, N 512 -> 128
    k_convpool<<<(128 / 32) * 2 * 128, 256, 0, stream>>>(P1, P2, pW2, pB2, ic2, ip2,
                                                         sc1, sh1, 64, 128, 512, 128, 1);
    k_stats<<<2 * 128, 256, 0, stream>>>(P2, pG2, pE2, sc2, sh2, 128, 128);

    // layer 3: 128 -> 256, N 128 -> 32
    k_convpool<<<(256 / 32) * 2 * 32, 256, 0, stream>>>(P2, P3, pW3, pB3, ic3, ip3,
                                                        sc2, sh2, 128, 256, 128, 32, 1);
    k_stats<<<2 * 256, 256, 0, stream>>>(P3, pG3, pE3, sc3, sh3, 256, 32);

    // layer 4: 256 -> 512, N 32 -> 8
    k_convpool<<<(512 / 32) * 2 * 8, 256, 0, stream>>>(P3, P4, pW4, pB4, ic4, ip4,
                                                       sc3, sh3, 256, 512, 32, 8, 1);
    k_stats<<<2 * 512, 256, 0, stream>>>(P4, pG4, pE4, sc4, sh4, 512, 8);

    // head
    k_zbuild<<<4096, 256, 0, stream>>>(P4, sc4, sh4, z);
    k_lin1<<<2048 / 16, 256, 0, stream>>>(z, lw1, lb1, o1);
    k_stats5<<<2048, 256, 0, stream>>>(o1, g5, e5, sc5, sh5);
    k_final<<<256, 256, 0, stream>>>(o1, sc5, sh5, lw2, lb2, (float*)d_out);
}

// Round 3
// 1235.865 us; speedup vs baseline: 7.5259x; 7.5259x over previous
//
#include <hip/hip_runtime.h>
#include <math.h>

#define B 256
#define KW 7

typedef __bf16 bf16x8 __attribute__((ext_vector_type(8)));
typedef __bf16 bf16x4 __attribute__((ext_vector_type(4)));
typedef float  f32x4  __attribute__((ext_vector_type(4)));

// ---------------------------------------------------------------------------
// helpers
// ---------------------------------------------------------------------------
__device__ __forceinline__ void block_reduce2(float& s, float& s2, float* lds) {
    for (int off = 32; off > 0; off >>= 1) {
        s  += __shfl_down(s,  off, 64);
        s2 += __shfl_down(s2, off, 64);
    }
    int wave = threadIdx.x >> 6;
    int lane = threadIdx.x & 63;
    if (lane == 0) { lds[wave * 2] = s; lds[wave * 2 + 1] = s2; }
    __syncthreads();
    if (threadIdx.x == 0) {
        s  = lds[0] + lds[2] + lds[4] + lds[6];
        s2 = lds[1] + lds[3] + lds[5] + lds[7];
    }
}

// ---------------------------------------------------------------------------
// x (B, 4, 2048) -> A0 [t][n][ci][b] fp32, LDS-tiled transpose
// ---------------------------------------------------------------------------
__global__ __launch_bounds__(256) void k_transpose(const float* __restrict__ x,
                                                   float* __restrict__ A0) {
    int bid = blockIdx.x;
    int nt  = bid & 63;
    int rem = bid >> 6;
    int ci  = rem & 1;
    int t   = rem >> 1;
    int n0  = nt * 32;
    __shared__ float lds[32][257];
    int tid = threadIdx.x;
    int nl  = tid & 31;
    int bq  = tid >> 5;
    int ch  = t * 2 + ci;
    for (int p = 0; p < 32; p++) {
        int b = bq + p * 8;
        lds[nl][b] = x[((size_t)b * 4 + ch) * 2048 + n0 + nl];
    }
    __syncthreads();
    for (int nl2 = 0; nl2 < 32; nl2++) {
        A0[(((size_t)t * 2048 + n0 + nl2) * 2 + ci) * B + tid] = lds[nl2][tid];
    }
}

// ---------------------------------------------------------------------------
// layer-1 fused conv+pool (fp32, Kt=14), output fp32 P1 [t][np][co][b]
// ---------------------------------------------------------------------------
__global__ __launch_bounds__(256) void k_convpool1(
    const float* __restrict__ act,      // [2][2048][2][256]
    float* __restrict__ P1,             // [2][512][64][256] fp32
    const float* __restrict__ w,        // [64][2][7]
    const float* __restrict__ bias,
    const int* __restrict__ idx_conv,   // [7][2048]
    const int* __restrict__ idx_pool)   // [7][512]
{
    const int Kt = 14, C_out = 64, N_in = 2048, N_out = 512;
    int bid   = blockIdx.x;
    int cot   = bid & 1;
    int colid = bid >> 1;
    int t     = colid / N_out;
    int np    = colid - t * N_out;
    int co0   = cot << 5;

    __shared__ float lds_g[14 * 256];
    __shared__ float lds_w[14 * 33];
    __shared__ int   lds_idx[KW];

    int tid = threadIdx.x;
    int cog = tid >> 6;
    int bl  = tid & 63;

    float pmax[8][4];
    #pragma unroll
    for (int i = 0; i < 8; i++)
        #pragma unroll
        for (int j = 0; j < 4; j++) pmax[i][j] = -INFINITY;

    const float* actT = act + (size_t)t * N_in * 2 * B;

    for (int kp = 0; kp < KW; kp++) {
        int nc = idx_pool[kp * N_out + np];
        if (tid < KW) lds_idx[tid] = idx_conv[tid * N_in + nc];

        float acc[8][4];
        #pragma unroll
        for (int i = 0; i < 8; i++)
            #pragma unroll
            for (int j = 0; j < 4; j++) acc[i][j] = 0.f;

        __syncthreads();
        for (int e = tid; e < 32 * Kt; e += 256) {
            int kk = e % Kt;
            int co = e / Kt;
            lds_w[kk * 33 + co] = w[(size_t)(co0 + co) * Kt + kk];
        }
        for (int r = 0; r < Kt; r++) {
            int ci  = r / KW;
            int k   = r - ci * KW;
            int col = lds_idx[k];
            lds_g[r * 256 + tid] = actT[((size_t)col * 2 + ci) * B + tid];
        }
        __syncthreads();
        for (int kk = 0; kk < Kt; kk++) {
            float g0 = lds_g[kk * 256 + bl];
            float g1 = lds_g[kk * 256 + bl + 64];
            float g2 = lds_g[kk * 256 + bl + 128];
            float g3 = lds_g[kk * 256 + bl + 192];
            const float* wr = lds_w + kk * 33 + cog * 8;
            #pragma unroll
            for (int i = 0; i < 8; i++) {
                float wv = wr[i];
                acc[i][0] = fmaf(wv, g0, acc[i][0]);
                acc[i][1] = fmaf(wv, g1, acc[i][1]);
                acc[i][2] = fmaf(wv, g2, acc[i][2]);
                acc[i][3] = fmaf(wv, g3, acc[i][3]);
            }
        }
        #pragma unroll
        for (int i = 0; i < 8; i++)
            #pragma unroll
            for (int j = 0; j < 4; j++) pmax[i][j] = fmaxf(pmax[i][j], acc[i][j]);
    }

    float* outp = P1 + (((size_t)t * N_out + np) * C_out + co0) * B;
    #pragma unroll
    for (int i = 0; i < 8; i++) {
        int co = cog * 8 + i;
        float bv = bias[co0 + co];
        #pragma unroll
        for (int j = 0; j < 4; j++)
            outp[(size_t)co * B + bl + 64 * j] = pmax[i][j] + bv;
    }
}

// ---------------------------------------------------------------------------
// stats over P1 fp32 [t][np][co][b] ; block per (t*64+c)
// ---------------------------------------------------------------------------
__global__ __launch_bounds__(256) void k_stats1(
    const float* __restrict__ P1,
    const float* __restrict__ gamma, const float* __restrict__ beta,
    float* __restrict__ scale, float* __restrict__ shift)
{
    int bid = blockIdx.x;
    int t = bid >> 6, c = bid & 63;
    const float* base = P1 + ((size_t)t * 512 * 64 + c) * B;
    float s = 0.f, s2 = 0.f;
    for (int n = 0; n < 512; n++) {
        float v = base[(size_t)n * 64 * B + threadIdx.x];
        s += v; s2 += v * v;
    }
    __shared__ float lds[8];
    block_reduce2(s, s2, lds);
    if (threadIdx.x == 0) {
        float cnt  = 512.f * 256.f;
        float m    = s / cnt;
        float var  = s2 / cnt - m * m;
        float istd = rsqrtf(var + 1e-5f);
        float g    = gamma[c];
        scale[bid] = istd * g;
        shift[bid] = beta[c] - m * istd * g;
    }
}

// ---------------------------------------------------------------------------
// BN+relu + transpose: P1 fp32 [t][np][co][b] -> act1 bf16 [t][np][b][co]
// (single bf16 rounding for layer-1 activation)
// ---------------------------------------------------------------------------
__global__ __launch_bounds__(256) void k_bnrelu1t(
    const float* __restrict__ P1,
    const float* __restrict__ sc, const float* __restrict__ sh,
    __bf16* __restrict__ act1)
{
    int bid = blockIdx.x;
    int t = bid >> 9;
    int b = threadIdx.x;
    const float* src = P1 + (size_t)bid * 64 * B;
    __bf16* dst = act1 + (size_t)bid * B * 64 + (size_t)b * 64;
    const float* scp = sc + t * 64;
    const float* shp = sh + t * 64;
    __bf16 vals[64];
    #pragma unroll
    for (int co = 0; co < 64; co++) {
        float v = src[co * B + b];
        vals[co] = (__bf16)fmaxf(fmaf(v, scp[co], shp[co]), 0.f);
    }
    #pragma unroll
    for (int j = 0; j < 8; j++)
        *(bf16x8*)(dst + j * 8) = *(bf16x8*)&vals[j * 8];
}

// ---------------------------------------------------------------------------
// weight re-layout: w [C_out][C_in][7] fp32 -> wr [C_out][7][C_in] bf16
// ---------------------------------------------------------------------------
__global__ void k_wr(const float* __restrict__ w, __bf16* __restrict__ wr,
                     int C_in, int total) {
    int idx = blockIdx.x * 256 + threadIdx.x;
    if (idx >= total) return;
    int ci = idx % C_in;
    int r  = idx / C_in;
    int kt = r % 7;
    int co = r / 7;
    wr[idx] = (__bf16)w[((size_t)co * C_in + ci) * 7 + kt];
}

__global__ void k_cvt(const float* __restrict__ src, __bf16* __restrict__ dst, int total) {
    int idx = blockIdx.x * 256 + threadIdx.x;
    if (idx >= total) return;
    dst[idx] = (__bf16)src[idx];
}

// ---------------------------------------------------------------------------
// MFMA conv for one branch t: act [t][N][256][C_in] bf16 x wr [C_out][7][C_in]
//   -> convo [N][256][C_out] fp32 (dense over all N columns, single t)
// block tile: 64 co x 256 b; grid (C_out/64) * N
// ---------------------------------------------------------------------------
__global__ __launch_bounds__(256) void k_conv_mfma(
    const __bf16* __restrict__ act,
    float* __restrict__ convo,
    const __bf16* __restrict__ wr,
    const int* __restrict__ idx_conv,   // [7][N]
    int C_in, int C_out, int N, int ci_shift, int t)
{
    int nco = C_out >> 6;
    int bid = blockIdx.x;
    int cot = bid % nco;
    int n   = bid / nco;
    int co0 = cot * 64;
    int Kt  = C_in * KW;

    __shared__ __bf16 lds_w[64 * 32];

    int tid  = threadIdx.x;
    int wv   = tid >> 6;
    int lane = tid & 63;
    int quad = lane >> 4;
    int lid  = lane & 15;

    f32x4 acc[4][4];
    #pragma unroll
    for (int i = 0; i < 4; i++)
        #pragma unroll
        for (int j = 0; j < 4; j++) {
            acc[i][j][0] = 0.f; acc[i][j][1] = 0.f;
            acc[i][j][2] = 0.f; acc[i][j][3] = 0.f;
        }

    const __bf16* actT = act + (size_t)t * N * B * C_in;
    int wco  = tid >> 2;
    int wseg = tid & 3;
    const __bf16* wsrc = wr + (size_t)(co0 + wco) * Kt + wseg * 8;

    for (int k0 = 0; k0 < Kt; k0 += 32) {
        int kt  = k0 >> ci_shift;
        int ci0 = k0 & (C_in - 1);
        int col = idx_conv[kt * N + n];
        __syncthreads();
        *(bf16x8*)&lds_w[wco * 32 + wseg * 8] = *(const bf16x8*)(wsrc + k0);
        __syncthreads();
        bf16x8 bfrag[4];
        const __bf16* gbase = actT + ((size_t)col * B + wv * 64 + lid) * C_in + ci0 + quad * 8;
        #pragma unroll
        for (int bt = 0; bt < 4; bt++)
            bfrag[bt] = *(const bf16x8*)(gbase + (size_t)bt * 16 * C_in);
        #pragma unroll
        for (int rt = 0; rt < 4; rt++) {
            bf16x8 afrag = *(const bf16x8*)&lds_w[(rt * 16 + lid) * 32 + quad * 8];
            #pragma unroll
            for (int bt = 0; bt < 4; bt++)
                acc[rt][bt] = __builtin_amdgcn_mfma_f32_16x16x32_bf16(
                    afrag, bfrag[bt], acc[rt][bt], 0, 0, 0);
        }
    }

    float* outp = convo + (size_t)n * B * C_out;
    #pragma unroll
    for (int rt = 0; rt < 4; rt++)
        #pragma unroll
        for (int bt = 0; bt < 4; bt++) {
            int b  = wv * 64 + bt * 16 + lid;
            int co = co0 + rt * 16 + quad * 4;
            *(f32x4*)(outp + (size_t)b * C_out + co) = acc[rt][bt];
        }
}

// ---------------------------------------------------------------------------
// pool + bias + stats partials (fp32): convo [N][256][C] -> P [t][No][256][C] fp32
// grid: No*4 (bg = 64-batch group), single t
// ---------------------------------------------------------------------------
__global__ __launch_bounds__(256) void k_poolstats(
    const float* __restrict__ convo,
    float* __restrict__ P,
    const float* __restrict__ bias,
    const int* __restrict__ idx_pool,   // [7][No]
    float* __restrict__ part,
    int C, int N, int No, int t)
{
    int bid = blockIdx.x;
    int bg  = bid & 3;
    int np  = bid >> 2;
    int cols[7];
    #pragma unroll
    for (int k = 0; k < 7; k++) cols[k] = idx_pool[k * No + np];
    float* pout = P + ((size_t)(t * No + np) * B) * C;
    int tid = threadIdx.x;
    float s[2] = {0.f, 0.f}, s2[2] = {0.f, 0.f};
    int NC, c0, bstart, bstep, nb;
    if (C >= 256) { NC = C >> 8; c0 = tid;       bstart = 0;        bstep = 1; nb = 64; }
    else          { NC = 1;      c0 = tid & (C - 1); bstart = tid >> 7; bstep = 2; nb = 32; }
    for (int j = 0; j < NC; j++) {
        int c = c0 + j * 256;
        float bv = bias[c];
        for (int i = 0; i < nb; i++) {
            int b = bg * 64 + bstart + i * bstep;
            float m = -1e30f;
            #pragma unroll
            for (int k = 0; k < 7; k++) {
                float v = convo[((size_t)cols[k] * B + b) * C + c];
                m = fmaxf(m, v);
            }
            float val = m + bv;
            pout[(size_t)b * C + c] = val;
            s[j] += val; s2[j] += val * val;
        }
    }
    float* pp = part + (size_t)((t * No + np) * 4 + bg) * 1024;
    for (int j = 0; j < NC; j++) {
        pp[tid + j * 256]       = s[j];
        pp[512 + tid + j * 256] = s2[j];
    }
}

// ---------------------------------------------------------------------------
// finalize BN stats from partials
// ---------------------------------------------------------------------------
__global__ void k_finstats(const float* __restrict__ part,
                           const float* __restrict__ gamma, const float* __restrict__ beta,
                           float* __restrict__ scale, float* __restrict__ shift,
                           int C, int No)
{
    int idx = blockIdx.x * 256 + threadIdx.x;
    if (idx >= 2 * C) return;
    int t = idx / C, c = idx - t * C;
    int SMAX = C < 256 ? 256 : C;
    float s = 0.f, s2 = 0.f;
    for (int np = 0; np < No; np++)
        for (int bg = 0; bg < 4; bg++) {
            const float* pp = part + (size_t)((t * No + np) * 4 + bg) * 1024;
            for (int sl = c; sl < SMAX; sl += C) { s += pp[sl]; s2 += pp[512 + sl]; }
        }
    float cnt  = (float)No * 256.f;
    float m    = s / cnt;
    float var  = s2 / cnt - m * m;
    float istd = rsqrtf(var + 1e-5f);
    float g    = gamma[c];
    scale[idx] = istd * g;
    shift[idx] = beta[c] - m * istd * g;
}

// ---------------------------------------------------------------------------
// BN+relu: P fp32 [2][No][256][C] -> act bf16 same layout (single rounding)
// ---------------------------------------------------------------------------
__global__ void k_bnrelu(const float* __restrict__ P, __bf16* __restrict__ act,
                         const float* __restrict__ scale, const float* __restrict__ shift,
                         int C, int total)
{
    int idx = blockIdx.x * 256 + threadIdx.x;
    if (idx >= total) return;
    int c = idx & (C - 1);
    int t = idx >= (total >> 1) ? 1 : 0;
    int tc = t * C + c;
    float v = P[idx];
    act[idx] = (__bf16)fmaxf(fmaf(v, scale[tc], shift[tc]), 0.f);
}

// ---------------------------------------------------------------------------
// z [b][4096] bf16 from P4 fp32 [2][8][256][512]: BN+relu+branch-avg in fp32,
// one bf16 rounding.  f = c*8 + np
// ---------------------------------------------------------------------------
__global__ __launch_bounds__(256) void k_zbuild(const float* __restrict__ P4,
                                                const float* __restrict__ sc4,
                                                const float* __restrict__ sh4,
                                                __bf16* __restrict__ z)
{
    int b = blockIdx.x;
    int tid = threadIdx.x;
    for (int j = 0; j < 2; j++) {
        int c = tid + j * 256;
        float s0 = sc4[c],       h0 = sh4[c];
        float s1 = sc4[512 + c], h1 = sh4[512 + c];
        #pragma unroll
        for (int np = 0; np < 8; np++) {
            float v0 = P4[(((size_t)0 * 8 + np) * B + b) * 512 + c];
            float v1 = P4[(((size_t)1 * 8 + np) * B + b) * 512 + c];
            float y0 = fmaxf(fmaf(v0, s0, h0), 0.f);
            float y1 = fmaxf(fmaf(v1, s1, h1), 0.f);
            z[(size_t)b * 4096 + c * 8 + np] = (__bf16)(0.5f * (y0 + y1));
        }
    }
}

// ---------------------------------------------------------------------------
// lin1 MFMA: o1[h][b] = sum_f w1b[h][f] * z[b][f] + b1[h]  (fp32 out)
// ---------------------------------------------------------------------------
__global__ __launch_bounds__(256) void k_lin1(
    const __bf16* __restrict__ zb,    // [256][4096]
    const __bf16* __restrict__ w1b,   // [2048][4096]
    const float* __restrict__ b1,
    float* __restrict__ o1)           // [2048][256]
{
    int h0 = blockIdx.x * 64;
    __shared__ __bf16 lds_w[64 * 32];

    int tid  = threadIdx.x;
    int wv   = tid >> 6;
    int lane = tid & 63;
    int quad = lane >> 4;
    int lid  = lane & 15;

    f32x4 acc[4][4];
    #pragma unroll
    for (int i = 0; i < 4; i++)
        #pragma unroll
        for (int j = 0; j < 4; j++) {
            acc[i][j][0] = 0.f; acc[i][j][1] = 0.f;
            acc[i][j][2] = 0.f; acc[i][j][3] = 0.f;
        }

    int wco  = tid >> 2;
    int wseg = tid & 3;
    const __bf16* wsrc = w1b + (size_t)(h0 + wco) * 4096 + wseg * 8;

    for (int f0 = 0; f0 < 4096; f0 += 32) {
        __syncthreads();
        *(bf16x8*)&lds_w[wco * 32 + wseg * 8] = *(const bf16x8*)(wsrc + f0);
        __syncthreads();
        bf16x8 bfrag[4];
        const __bf16* gbase = zb + (size_t)(wv * 64 + lid) * 4096 + f0 + quad * 8;
        #pragma unroll
        for (int bt = 0; bt < 4; bt++)
            bfrag[bt] = *(const bf16x8*)(gbase + (size_t)bt * 16 * 4096);
        #pragma unroll
        for (int rt = 0; rt < 4; rt++) {
            bf16x8 afrag = *(const bf16x8*)&lds_w[(rt * 16 + lid) * 32 + quad * 8];
            #pragma unroll
            for (int bt = 0; bt < 4; bt++)
                acc[rt][bt] = __builtin_amdgcn_mfma_f32_16x16x32_bf16(
                    afrag, bfrag[bt], acc[rt][bt], 0, 0, 0);
        }
    }
    #pragma unroll
    for (int rt = 0; rt < 4; rt++)
        #pragma unroll
        for (int bt = 0; bt < 4; bt++) {
            int b = wv * 64 + bt * 16 + lid;
            int h = h0 + rt * 16 + quad * 4;
            #pragma unroll
            for (int r = 0; r < 4; r++)
                o1[(size_t)(h + r) * B + b] = acc[rt][bt][r] + b1[h + r];
        }
}

// ---------------------------------------------------------------------------
// BN5 stats per h over batch
// ---------------------------------------------------------------------------
__global__ __launch_bounds__(256) void k_stats5(
    const float* __restrict__ o1,
    const float* __restrict__ gamma5, const float* __restrict__ beta5,
    float* __restrict__ scale5, float* __restrict__ shift5)
{
    int h = blockIdx.x;
    float v = o1[(size_t)h * B + threadIdx.x];
    float s = v, s2 = v * v;
    __shared__ float lds[8];
    block_reduce2(s, s2, lds);
    if (threadIdx.x == 0) {
        float m    = s * (1.f / 256.f);
        float var  = s2 * (1.f / 256.f) - m * m;
        float istd = rsqrtf(var + 1e-5f);
        float g    = gamma5[h];
        scale5[h]  = istd * g;
        shift5[h]  = beta5[h] - m * istd * g;
    }
}

// ---------------------------------------------------------------------------
// final head
// ---------------------------------------------------------------------------
__global__ __launch_bounds__(256) void k_final(
    const float* __restrict__ o1,
    const float* __restrict__ scale5, const float* __restrict__ shift5,
    const float* __restrict__ w2, const float* __restrict__ b2,
    float* __restrict__ out)
{
    int b = blockIdx.x;
    int tid = threadIdx.x;
    float s0 = 0.f, s1 = 0.f, s2v = 0.f;
    for (int h = tid; h < 2048; h += 256) {
        float y = fmaxf(fmaf(o1[(size_t)h * B + b], scale5[h], shift5[h]), 0.f);
        s0  = fmaf(y, w2[h],        s0);
        s1  = fmaf(y, w2[2048 + h], s1);
        s2v = fmaf(y, w2[4096 + h], s2v);
    }
    for (int off = 32; off > 0; off >>= 1) {
        s0  += __shfl_down(s0,  off, 64);
        s1  += __shfl_down(s1,  off, 64);
        s2v += __shfl_down(s2v, off, 64);
    }
    __shared__ float lds[12];
    int wave = tid >> 6, lane = tid & 63;
    if (lane == 0) { lds[wave * 3] = s0; lds[wave * 3 + 1] = s1; lds[wave * 3 + 2] = s2v; }
    __syncthreads();
    if (tid == 0) {
        float o0 = lds[0] + lds[3] + lds[6] + lds[9]  + b2[0];
        float oa = lds[1] + lds[4] + lds[7] + lds[10] + b2[1];
        float ob = lds[2] + lds[5] + lds[8] + lds[11] + b2[2];
        float m   = fmaxf(o0, oa);
        float lse = m + logf(expf(o0 - m) + expf(oa - m));
        out[b * 3 + 0] = o0 - lse;
        out[b * 3 + 1] = oa - lse;
        out[b * 3 + 2] = ob;
    }
}

// ---------------------------------------------------------------------------
extern "C" void kernel_launch(void* const* d_in, const int* in_sizes, int n_in,
                              void* d_out, int out_size, void* d_ws, size_t ws_size,
                              hipStream_t stream) {
    (void)in_sizes; (void)n_in; (void)out_size; (void)ws_size;

    const float* x   = (const float*)d_in[0];
    const int*   ic1 = (const int*)d_in[1];
    const int*   ip1 = (const int*)d_in[2];
    const float* pW1 = (const float*)d_in[3];
    const float* pB1 = (const float*)d_in[4];
    const float* pG1 = (const float*)d_in[5];
    const float* pE1 = (const float*)d_in[6];
    const int*   ic2 = (const int*)d_in[7];
    const int*   ip2 = (const int*)d_in[8];
    const float* pW2 = (const float*)d_in[9];
    const float* pB2 = (const float*)d_in[10];
    const float* pG2 = (const float*)d_in[11];
    const float* pE2 = (const float*)d_in[12];
    const int*   ic3 = (const int*)d_in[13];
    const int*   ip3 = (const int*)d_in[14];
    const float* pW3 = (const float*)d_in[15];
    const float* pB3 = (const float*)d_in[16];
    const float* pG3 = (const float*)d_in[17];
    const float* pE3 = (const float*)d_in[18];
    const int*   ic4 = (const int*)d_in[19];
    const int*   ip4 = (const int*)d_in[20];
    const float* pW4 = (const float*)d_in[21];
    const float* pB4 = (const float*)d_in[22];
    const float* pG4 = (const float*)d_in[23];
    const float* pE4 = (const float*)d_in[24];
    const float* lw1 = (const float*)d_in[25];
    const float* lb1 = (const float*)d_in[26];
    const float* g5  = (const float*)d_in[27];
    const float* e5  = (const float*)d_in[28];
    const float* lw2 = (const float*)d_in[29];
    const float* lb2 = (const float*)d_in[30];

    char* ws = (char*)d_ws;
    size_t off = 0;
    auto alloc = [&](size_t bytes) -> char* {
        char* p = ws + off;
        off += (bytes + 511) & ~(size_t)511;
        return p;
    };

    // layout (with aliasing): total ~185 MB
    float*  A0    = (float*) alloc((size_t)2 * 2048 * 2 * B * 4);      //   8.4 MB
    __bf16* act1  = (__bf16*)alloc((size_t)2 * 512 * B * 64 * 2);      //  33.5 MB
    char*   U     =          alloc((size_t)512 * B * 128 * 4);         //  67.1 MB (P1f, then convXf per-t)
    float*  P1f   = (float*)U;            // [2][512][64][256] fp32 = 67.1 MB, dead after bnrelu1t
    float*  convX = (float*)U;            // per-t conv out, max 512*256*128 fp32 = 67.1 MB
    float*  Pf    = (float*) alloc((size_t)2 * 128 * B * 128 * 4);     //  33.5 MB (P2f/P3f/P4f shared)
    __bf16* actS  = (__bf16*)alloc((size_t)2 * 128 * B * 128 * 2);     //  16.8 MB (act2/act3 shared)
    __bf16* Wr2   = (__bf16*)alloc((size_t)128 * 448 * 2);
    __bf16* Wr3   = (__bf16*)alloc((size_t)256 * 896 * 2);
    __bf16* Wr4   = (__bf16*)alloc((size_t)512 * 1792 * 2);
    __bf16* w1b   = (__bf16*)alloc((size_t)2048 * 4096 * 2);           //  16.8 MB
    __bf16* z     = (__bf16*)alloc((size_t)256 * 4096 * 2);            //   2.1 MB
    float*  o1    = (float*) alloc((size_t)2048 * B * 4);              //   2.1 MB
    float*  part  = (float*) alloc((size_t)2 * 128 * 4 * 1024 * 4);    //   4.2 MB
    float*  sc1 = (float*)alloc(2 * 64 * 4);
    float*  sh1 = (float*)alloc(2 * 64 * 4);
    float*  sc2 = (float*)alloc(2 * 128 * 4);
    float*  sh2 = (float*)alloc(2 * 128 * 4);
    float*  sc3 = (float*)alloc(2 * 256 * 4);
    float*  sh3 = (float*)alloc(2 * 256 * 4);
    float*  sc4 = (float*)alloc(2 * 512 * 4);
    float*  sh4 = (float*)alloc(2 * 512 * 4);
    float*  sc5 = (float*)alloc(2048 * 4);
    float*  sh5 = (float*)alloc(2048 * 4);

    // weight prep
    k_wr<<<(128 * 448 + 255) / 256, 256, 0, stream>>>(pW2, Wr2, 64, 128 * 448);
    k_wr<<<(256 * 896 + 255) / 256, 256, 0, stream>>>(pW3, Wr3, 128, 256 * 896);
    k_wr<<<(512 * 1792 + 255) / 256, 256, 0, stream>>>(pW4, Wr4, 256, 512 * 1792);
    k_cvt<<<(2048 * 4096) / 256, 256, 0, stream>>>(lw1, w1b, 2048 * 4096);

    // input transform
    k_transpose<<<256, 256, 0, stream>>>(x, A0);

    // layer 1 (fp32 throughout; single bf16 rounding in bnrelu1t)
    k_convpool1<<<2048, 256, 0, stream>>>(A0, P1f, pW1, pB1, ic1, ip1);
    k_stats1<<<2 * 64, 256, 0, stream>>>(P1f, pG1, pE1, sc1, sh1);
    k_bnrelu1t<<<2 * 512, 256, 0, stream>>>(P1f, sc1, sh1, act1);

    // layer 2: 64 -> 128, N 512 -> 128 (per-branch through convX)
    for (int t = 0; t < 2; t++) {
        k_conv_mfma<<<2 * 512, 256, 0, stream>>>(act1, convX, Wr2, ic2, 64, 128, 512, 6, t);
        k_poolstats<<<128 * 4, 256, 0, stream>>>(convX, Pf, pB2, ip2, part, 128, 512, 128, t);
    }
    k_finstats<<<1, 256, 0, stream>>>(part, pG2, pE2, sc2, sh2, 128, 128);
    k_bnrelu<<<(2 * 128 * B * 128) / 256, 256, 0, stream>>>(Pf, actS, sc2, sh2, 128, 2 * 128 * B * 128);

    // layer 3: 128 -> 256, N 128 -> 32
    for (int t = 0; t < 2; t++) {
        k_conv_mfma<<<4 * 128, 256, 0, stream>>>(actS, convX, Wr3, ic3, 128, 256, 128, 7, t);
        k_poolstats<<<32 * 4, 256, 0, stream>>>(convX, Pf, pB3, ip3, part, 256, 128, 32, t);
    }
    k_finstats<<<2, 256, 0, stream>>>(part, pG3, pE3, sc3, sh3, 256, 32);
    k_bnrelu<<<(2 * 32 * B * 256) / 256, 256, 0, stream>>>(Pf, actS, sc3, sh3, 256, 2 * 32 * B * 256);

    // layer 4: 256 -> 512, N 32 -> 8
    for (int t = 0; t < 2; t++) {
        k_conv_mfma<<<8 * 32, 256, 0, stream>>>(actS, convX, Wr4, ic4, 256, 512, 32, 8, t);
        k_poolstats<<<8 * 4, 256, 0, stream>>>(convX, Pf, pB4, ip4, part, 512, 32, 8, t);
    }
    k_finstats<<<4, 256, 0, stream>>>(part, pG4, pE4, sc4, sh4, 512, 8);

    // head (zbuild applies BN4+relu+avg in fp32, rounds once)
    k_zbuild<<<256, 256, 0, stream>>>(Pf, sc4, sh4, z);
    k_lin1<<<32, 256, 0, stream>>>(z, w1b, lb1, o1);
    k_stats5<<<2048, 256, 0, stream>>>(o1, g5, e5, sc5, sh5);
    k_final<<<256, 256, 0, stream>>>(o1, sc5, sh5, lw2, lb2, (float*)d_out);
}

// Round 4
// 917.620 us; speedup vs baseline: 10.1360x; 1.3468x over previous
//
#include <hip/hip_runtime.h>
#include <math.h>

#define B 256
#define KW 7

typedef __bf16 bf16x8 __attribute__((ext_vector_type(8)));
typedef __bf16 bf16x4 __attribute__((ext_vector_type(4)));
typedef float  f32x4  __attribute__((ext_vector_type(4)));

// ---------------------------------------------------------------------------
// helpers
// ---------------------------------------------------------------------------
__device__ __forceinline__ void block_reduce2(float& s, float& s2, float* lds) {
    for (int off = 32; off > 0; off >>= 1) {
        s  += __shfl_down(s,  off, 64);
        s2 += __shfl_down(s2, off, 64);
    }
    int wave = threadIdx.x >> 6;
    int lane = threadIdx.x & 63;
    if (lane == 0) { lds[wave * 2] = s; lds[wave * 2 + 1] = s2; }
    __syncthreads();
    if (threadIdx.x == 0) {
        s  = lds[0] + lds[2] + lds[4] + lds[6];
        s2 = lds[1] + lds[3] + lds[5] + lds[7];
    }
}

// ---------------------------------------------------------------------------
// x (B, 4, 2048) -> A0 [t][n][ci][b] fp32, LDS-tiled transpose
// ---------------------------------------------------------------------------
__global__ __launch_bounds__(256) void k_transpose(const float* __restrict__ x,
                                                   float* __restrict__ A0) {
    int bid = blockIdx.x;
    int nt  = bid & 63;
    int rem = bid >> 6;
    int ci  = rem & 1;
    int t   = rem >> 1;
    int n0  = nt * 32;
    __shared__ float lds[32][257];
    int tid = threadIdx.x;
    int nl  = tid & 31;
    int bq  = tid >> 5;
    int ch  = t * 2 + ci;
    for (int p = 0; p < 32; p++) {
        int b = bq + p * 8;
        lds[nl][b] = x[((size_t)b * 4 + ch) * 2048 + n0 + nl];
    }
    __syncthreads();
    for (int nl2 = 0; nl2 < 32; nl2++) {
        A0[(((size_t)t * 2048 + n0 + nl2) * 2 + ci) * B + tid] = lds[nl2][tid];
    }
}

// ---------------------------------------------------------------------------
// layer-1 fused conv+pool (fp32, Kt=14), output fp32 P1 [t][np][co][b]
// ---------------------------------------------------------------------------
__global__ __launch_bounds__(256) void k_convpool1(
    const float* __restrict__ act,      // [2][2048][2][256]
    float* __restrict__ P1,             // [2][512][64][256] fp32
    const float* __restrict__ w,        // [64][2][7]
    const float* __restrict__ bias,
    const int* __restrict__ idx_conv,   // [7][2048]
    const int* __restrict__ idx_pool)   // [7][512]
{
    const int Kt = 14, C_out = 64, N_in = 2048, N_out = 512;
    int bid   = blockIdx.x;
    int cot   = bid & 1;
    int colid = bid >> 1;
    int t     = colid / N_out;
    int np    = colid - t * N_out;
    int co0   = cot << 5;

    __shared__ float lds_g[14 * 256];
    __shared__ float lds_w[14 * 33];
    __shared__ int   lds_idx[KW];

    int tid = threadIdx.x;
    int cog = tid >> 6;
    int bl  = tid & 63;

    float pmax[8][4];
    #pragma unroll
    for (int i = 0; i < 8; i++)
        #pragma unroll
        for (int j = 0; j < 4; j++) pmax[i][j] = -INFINITY;

    const float* actT = act + (size_t)t * N_in * 2 * B;

    for (int kp = 0; kp < KW; kp++) {
        int nc = idx_pool[kp * N_out + np];
        if (tid < KW) lds_idx[tid] = idx_conv[tid * N_in + nc];

        float acc[8][4];
        #pragma unroll
        for (int i = 0; i < 8; i++)
            #pragma unroll
            for (int j = 0; j < 4; j++) acc[i][j] = 0.f;

        __syncthreads();
        for (int e = tid; e < 32 * Kt; e += 256) {
            int kk = e % Kt;
            int co = e / Kt;
            lds_w[kk * 33 + co] = w[(size_t)(co0 + co) * Kt + kk];
        }
        for (int r = 0; r < Kt; r++) {
            int ci  = r / KW;
            int k   = r - ci * KW;
            int col = lds_idx[k];
            lds_g[r * 256 + tid] = actT[((size_t)col * 2 + ci) * B + tid];
        }
        __syncthreads();
        for (int kk = 0; kk < Kt; kk++) {
            float g0 = lds_g[kk * 256 + bl];
            float g1 = lds_g[kk * 256 + bl + 64];
            float g2 = lds_g[kk * 256 + bl + 128];
            float g3 = lds_g[kk * 256 + bl + 192];
            const float* wr = lds_w + kk * 33 + cog * 8;
            #pragma unroll
            for (int i = 0; i < 8; i++) {
                float wv = wr[i];
                acc[i][0] = fmaf(wv, g0, acc[i][0]);
                acc[i][1] = fmaf(wv, g1, acc[i][1]);
                acc[i][2] = fmaf(wv, g2, acc[i][2]);
                acc[i][3] = fmaf(wv, g3, acc[i][3]);
            }
        }
        #pragma unroll
        for (int i = 0; i < 8; i++)
            #pragma unroll
            for (int j = 0; j < 4; j++) pmax[i][j] = fmaxf(pmax[i][j], acc[i][j]);
    }

    float* outp = P1 + (((size_t)t * N_out + np) * C_out + co0) * B;
    #pragma unroll
    for (int i = 0; i < 8; i++) {
        int co = cog * 8 + i;
        float bv = bias[co0 + co];
        #pragma unroll
        for (int j = 0; j < 4; j++)
            outp[(size_t)co * B + bl + 64 * j] = pmax[i][j] + bv;
    }
}

// ---------------------------------------------------------------------------
// stats over P1 fp32 [t][np][co][b] ; block per (t*64+c)
// ---------------------------------------------------------------------------
__global__ __launch_bounds__(256) void k_stats1(
    const float* __restrict__ P1,
    const float* __restrict__ gamma, const float* __restrict__ beta,
    float* __restrict__ scale, float* __restrict__ shift)
{
    int bid = blockIdx.x;
    int t = bid >> 6, c = bid & 63;
    const float* base = P1 + ((size_t)t * 512 * 64 + c) * B;
    float s = 0.f, s2 = 0.f;
    for (int n = 0; n < 512; n++) {
        float v = base[(size_t)n * 64 * B + threadIdx.x];
        s += v; s2 += v * v;
    }
    __shared__ float lds[8];
    block_reduce2(s, s2, lds);
    if (threadIdx.x == 0) {
        float cnt  = 512.f * 256.f;
        float m    = s / cnt;
        float var  = s2 / cnt - m * m;
        float istd = rsqrtf(var + 1e-5f);
        float g    = gamma[c];
        scale[bid] = istd * g;
        shift[bid] = beta[c] - m * istd * g;
    }
}

// ---------------------------------------------------------------------------
// BN+relu + transpose: P1 fp32 [t][np][co][b] -> act1 bf16 [t][np][b][co]
// ---------------------------------------------------------------------------
__global__ __launch_bounds__(256) void k_bnrelu1t(
    const float* __restrict__ P1,
    const float* __restrict__ sc, const float* __restrict__ sh,
    __bf16* __restrict__ act1)
{
    int bid = blockIdx.x;
    int t = bid >> 9;
    int b = threadIdx.x;
    const float* src = P1 + (size_t)bid * 64 * B;
    __bf16* dst = act1 + (size_t)bid * B * 64 + (size_t)b * 64;
    const float* scp = sc + t * 64;
    const float* shp = sh + t * 64;
    __bf16 vals[64];
    #pragma unroll
    for (int co = 0; co < 64; co++) {
        float v = src[co * B + b];
        vals[co] = (__bf16)fmaxf(fmaf(v, scp[co], shp[co]), 0.f);
    }
    #pragma unroll
    for (int j = 0; j < 8; j++)
        *(bf16x8*)(dst + j * 8) = *(bf16x8*)&vals[j * 8];
}

// ---------------------------------------------------------------------------
// weight re-layout: w [C_out][C_in][7] fp32 -> wr [C_out][7][C_in] bf16
// ---------------------------------------------------------------------------
__global__ void k_wr(const float* __restrict__ w, __bf16* __restrict__ wr,
                     int C_in, int total) {
    int idx = blockIdx.x * 256 + threadIdx.x;
    if (idx >= total) return;
    int ci = idx % C_in;
    int r  = idx / C_in;
    int kt = r % 7;
    int co = r / 7;
    wr[idx] = (__bf16)w[((size_t)co * C_in + ci) * 7 + kt];
}

__global__ void k_cvt(const float* __restrict__ src, __bf16* __restrict__ dst, int total) {
    int idx = blockIdx.x * 256 + threadIdx.x;
    if (idx >= total) return;
    dst[idx] = (__bf16)src[idx];
}

// ---------------------------------------------------------------------------
// MFMA conv for one branch t: act [t][N][256][C_in] bf16 x wr [C_out][7][C_in]
//   -> convo [N][256][C_out] fp32
// ---------------------------------------------------------------------------
__global__ __launch_bounds__(256) void k_conv_mfma(
    const __bf16* __restrict__ act,
    float* __restrict__ convo,
    const __bf16* __restrict__ wr,
    const int* __restrict__ idx_conv,   // [7][N]
    int C_in, int C_out, int N, int ci_shift, int t)
{
    int nco = C_out >> 6;
    int bid = blockIdx.x;
    int cot = bid % nco;
    int n   = bid / nco;
    int co0 = cot * 64;
    int Kt  = C_in * KW;

    __shared__ __bf16 lds_w[64 * 32];

    int tid  = threadIdx.x;
    int wv   = tid >> 6;
    int lane = tid & 63;
    int quad = lane >> 4;
    int lid  = lane & 15;

    f32x4 acc[4][4];
    #pragma unroll
    for (int i = 0; i < 4; i++)
        #pragma unroll
        for (int j = 0; j < 4; j++) {
            acc[i][j][0] = 0.f; acc[i][j][1] = 0.f;
            acc[i][j][2] = 0.f; acc[i][j][3] = 0.f;
        }

    const __bf16* actT = act + (size_t)t * N * B * C_in;
    int wco  = tid >> 2;
    int wseg = tid & 3;
    const __bf16* wsrc = wr + (size_t)(co0 + wco) * Kt + wseg * 8;

    for (int k0 = 0; k0 < Kt; k0 += 32) {
        int kt  = k0 >> ci_shift;
        int ci0 = k0 & (C_in - 1);
        int col = idx_conv[kt * N + n];
        __syncthreads();
        *(bf16x8*)&lds_w[wco * 32 + wseg * 8] = *(const bf16x8*)(wsrc + k0);
        __syncthreads();
        bf16x8 bfrag[4];
        const __bf16* gbase = actT + ((size_t)col * B + wv * 64 + lid) * C_in + ci0 + quad * 8;
        #pragma unroll
        for (int bt = 0; bt < 4; bt++)
            bfrag[bt] = *(const bf16x8*)(gbase + (size_t)bt * 16 * C_in);
        #pragma unroll
        for (int rt = 0; rt < 4; rt++) {
            bf16x8 afrag = *(const bf16x8*)&lds_w[(rt * 16 + lid) * 32 + quad * 8];
            #pragma unroll
            for (int bt = 0; bt < 4; bt++)
                acc[rt][bt] = __builtin_amdgcn_mfma_f32_16x16x32_bf16(
                    afrag, bfrag[bt], acc[rt][bt], 0, 0, 0);
        }
    }

    float* outp = convo + (size_t)n * B * C_out;
    #pragma unroll
    for (int rt = 0; rt < 4; rt++)
        #pragma unroll
        for (int bt = 0; bt < 4; bt++) {
            int b  = wv * 64 + bt * 16 + lid;
            int co = co0 + rt * 16 + quad * 4;
            *(f32x4*)(outp + (size_t)b * C_out + co) = acc[rt][bt];
        }
}

// ---------------------------------------------------------------------------
// pool + bias + stats partials (fp32): convo [N][256][C] -> P [t][No][256][C] fp32
// ---------------------------------------------------------------------------
__global__ __launch_bounds__(256) void k_poolstats(
    const float* __restrict__ convo,
    float* __restrict__ P,
    const float* __restrict__ bias,
    const int* __restrict__ idx_pool,   // [7][No]
    float* __restrict__ part,
    int C, int N, int No, int t)
{
    int bid = blockIdx.x;
    int bg  = bid & 3;
    int np  = bid >> 2;
    int cols[7];
    #pragma unroll
    for (int k = 0; k < 7; k++) cols[k] = idx_pool[k * No + np];
    float* pout = P + ((size_t)(t * No + np) * B) * C;
    int tid = threadIdx.x;
    float s[2] = {0.f, 0.f}, s2[2] = {0.f, 0.f};
    int NC, c0, bstart, bstep, nb;
    if (C >= 256) { NC = C >> 8; c0 = tid;       bstart = 0;        bstep = 1; nb = 64; }
    else          { NC = 1;      c0 = tid & (C - 1); bstart = tid >> 7; bstep = 2; nb = 32; }
    for (int j = 0; j < NC; j++) {
        int c = c0 + j * 256;
        float bv = bias[c];
        for (int i = 0; i < nb; i++) {
            int b = bg * 64 + bstart + i * bstep;
            float m = -1e30f;
            #pragma unroll
            for (int k = 0; k < 7; k++) {
                float v = convo[((size_t)cols[k] * B + b) * C + c];
                m = fmaxf(m, v);
            }
            float val = m + bv;
            pout[(size_t)b * C + c] = val;
            s[j] += val; s2[j] += val * val;
        }
    }
    float* pp = part + (size_t)((t * No + np) * 4 + bg) * 1024;
    for (int j = 0; j < NC; j++) {
        pp[tid + j * 256]       = s[j];
        pp[512 + tid + j * 256] = s2[j];
    }
}

// ---------------------------------------------------------------------------
// finalize BN stats from partials — PARALLEL version:
// one block per (t,c), 256 threads stride over the No*4*nslice partial entries.
// ---------------------------------------------------------------------------
__global__ __launch_bounds__(256) void k_finstats(
    const float* __restrict__ part,
    const float* __restrict__ gamma, const float* __restrict__ beta,
    float* __restrict__ scale, float* __restrict__ shift,
    int C, int No)
{
    int idx = blockIdx.x;            // t*C + c
    int t = idx / C, c = idx - t * C;
    int SMAX   = C < 256 ? 256 : C;
    int nslice = SMAX / C;           // 2 for C=128, 1 for C>=256
    int nblk   = No * 4;
    int total  = nblk * nslice;
    const float* pbase = part + (size_t)(t * No * 4) * 1024;
    float s = 0.f, s2 = 0.f;
    for (int e = threadIdx.x; e < total; e += 256) {
        int blk = e / nslice;
        int j   = e - blk * nslice;
        const float* pp = pbase + (size_t)blk * 1024;
        int sl = c + j * C;
        s  += pp[sl];
        s2 += pp[512 + sl];
    }
    __shared__ float lds[8];
    block_reduce2(s, s2, lds);
    if (threadIdx.x == 0) {
        float cnt  = (float)No * 256.f;
        float m    = s / cnt;
        float var  = s2 / cnt - m * m;
        float istd = rsqrtf(var + 1e-5f);
        float g    = gamma[c];
        scale[idx] = istd * g;
        shift[idx] = beta[c] - m * istd * g;
    }
}

// ---------------------------------------------------------------------------
// BN+relu: P fp32 [2][No][256][C] -> act bf16 same layout (single rounding)
// ---------------------------------------------------------------------------
__global__ void k_bnrelu(const float* __restrict__ P, __bf16* __restrict__ act,
                         const float* __restrict__ scale, const float* __restrict__ shift,
                         int C, int total)
{
    int idx = blockIdx.x * 256 + threadIdx.x;
    if (idx >= total) return;
    int c = idx & (C - 1);
    int t = idx >= (total >> 1) ? 1 : 0;
    int tc = t * C + c;
    float v = P[idx];
    act[idx] = (__bf16)fmaxf(fmaf(v, scale[tc], shift[tc]), 0.f);
}

// ---------------------------------------------------------------------------
// z [b][4096] bf16 from P4 fp32 [2][8][256][512]: BN+relu+avg in fp32, one rounding
// ---------------------------------------------------------------------------
__global__ __launch_bounds__(256) void k_zbuild(const float* __restrict__ P4,
                                                const float* __restrict__ sc4,
                                                const float* __restrict__ sh4,
                                                __bf16* __restrict__ z)
{
    int b = blockIdx.x;
    int tid = threadIdx.x;
    for (int j = 0; j < 2; j++) {
        int c = tid + j * 256;
        float s0 = sc4[c],       h0 = sh4[c];
        float s1 = sc4[512 + c], h1 = sh4[512 + c];
        #pragma unroll
        for (int np = 0; np < 8; np++) {
            float v0 = P4[(((size_t)0 * 8 + np) * B + b) * 512 + c];
            float v1 = P4[(((size_t)1 * 8 + np) * B + b) * 512 + c];
            float y0 = fmaxf(fmaf(v0, s0, h0), 0.f);
            float y1 = fmaxf(fmaf(v1, s1, h1), 0.f);
            z[(size_t)b * 4096 + c * 8 + np] = (__bf16)(0.5f * (y0 + y1));
        }
    }
}

// ---------------------------------------------------------------------------
// lin1 MFMA: o1[h][b] = sum_f w1b[h][f] * z[b][f] + b1[h]  (fp32 out)
// ---------------------------------------------------------------------------
__global__ __launch_bounds__(256) void k_lin1(
    const __bf16* __restrict__ zb,    // [256][4096]
    const __bf16* __restrict__ w1b,   // [2048][4096]
    const float* __restrict__ b1,
    float* __restrict__ o1)           // [2048][256]
{
    int h0 = blockIdx.x * 64;
    __shared__ __bf16 lds_w[64 * 32];

    int tid  = threadIdx.x;
    int wv   = tid >> 6;
    int lane = tid & 63;
    int quad = lane >> 4;
    int lid  = lane & 15;

    f32x4 acc[4][4];
    #pragma unroll
    for (int i = 0; i < 4; i++)
        #pragma unroll
        for (int j = 0; j < 4; j++) {
            acc[i][j][0] = 0.f; acc[i][j][1] = 0.f;
            acc[i][j][2] = 0.f; acc[i][j][3] = 0.f;
        }

    int wco  = tid >> 2;
    int wseg = tid & 3;
    const __bf16* wsrc = w1b + (size_t)(h0 + wco) * 4096 + wseg * 8;

    for (int f0 = 0; f0 < 4096; f0 += 32) {
        __syncthreads();
        *(bf16x8*)&lds_w[wco * 32 + wseg * 8] = *(const bf16x8*)(wsrc + f0);
        __syncthreads();
        bf16x8 bfrag[4];
        const __bf16* gbase = zb + (size_t)(wv * 64 + lid) * 4096 + f0 + quad * 8;
        #pragma unroll
        for (int bt = 0; bt < 4; bt++)
            bfrag[bt] = *(const bf16x8*)(gbase + (size_t)bt * 16 * 4096);
        #pragma unroll
        for (int rt = 0; rt < 4; rt++) {
            bf16x8 afrag = *(const bf16x8*)&lds_w[(rt * 16 + lid) * 32 + quad * 8];
            #pragma unroll
            for (int bt = 0; bt < 4; bt++)
                acc[rt][bt] = __builtin_amdgcn_mfma_f32_16x16x32_bf16(
                    afrag, bfrag[bt], acc[rt][bt], 0, 0, 0);
        }
    }
    #pragma unroll
    for (int rt = 0; rt < 4; rt++)
        #pragma unroll
        for (int bt = 0; bt < 4; bt++) {
            int b = wv * 64 + bt * 16 + lid;
            int h = h0 + rt * 16 + quad * 4;
            #pragma unroll
            for (int r = 0; r < 4; r++)
                o1[(size_t)(h + r) * B + b] = acc[rt][bt][r] + b1[h + r];
        }
}

// ---------------------------------------------------------------------------
// BN5 stats per h over batch
// ---------------------------------------------------------------------------
__global__ __launch_bounds__(256) void k_stats5(
    const float* __restrict__ o1,
    const float* __restrict__ gamma5, const float* __restrict__ beta5,
    float* __restrict__ scale5, float* __restrict__ shift5)
{
    int h = blockIdx.x;
    float v = o1[(size_t)h * B + threadIdx.x];
    float s = v, s2 = v * v;
    __shared__ float lds[8];
    block_reduce2(s, s2, lds);
    if (threadIdx.x == 0) {
        float m    = s * (1.f / 256.f);
        float var  = s2 * (1.f / 256.f) - m * m;
        float istd = rsqrtf(var + 1e-5f);
        float g    = gamma5[h];
        scale5[h]  = istd * g;
        shift5[h]  = beta5[h] - m * istd * g;
    }
}

// ---------------------------------------------------------------------------
// final head
// ---------------------------------------------------------------------------
__global__ __launch_bounds__(256) void k_final(
    const float* __restrict__ o1,
    const float* __restrict__ scale5, const float* __restrict__ shift5,
    const float* __restrict__ w2, const float* __restrict__ b2,
    float* __restrict__ out)
{
    int b = blockIdx.x;
    int tid = threadIdx.x;
    float s0 = 0.f, s1 = 0.f, s2v = 0.f;
    for (int h = tid; h < 2048; h += 256) {
        float y = fmaxf(fmaf(o1[(size_t)h * B + b], scale5[h], shift5[h]), 0.f);
        s0  = fmaf(y, w2[h],        s0);
        s1  = fmaf(y, w2[2048 + h], s1);
        s2v = fmaf(y, w2[4096 + h], s2v);
    }
    for (int off = 32; off > 0; off >>= 1) {
        s0  += __shfl_down(s0,  off, 64);
        s1  += __shfl_down(s1,  off, 64);
        s2v += __shfl_down(s2v, off, 64);
    }
    __shared__ float lds[12];
    int wave = tid >> 6, lane = tid & 63;
    if (lane == 0) { lds[wave * 3] = s0; lds[wave * 3 + 1] = s1; lds[wave * 3 + 2] = s2v; }
    __syncthreads();
    if (tid == 0) {
        float o0 = lds[0] + lds[3] + lds[6] + lds[9]  + b2[0];
        float oa = lds[1] + lds[4] + lds[7] + lds[10] + b2[1];
        float ob = lds[2] + lds[5] + lds[8] + lds[11] + b2[2];
        float m   = fmaxf(o0, oa);
        float lse = m + logf(expf(o0 - m) + expf(oa - m));
        out[b * 3 + 0] = o0 - lse;
        out[b * 3 + 1] = oa - lse;
        out[b * 3 + 2] = ob;
    }
}

// ---------------------------------------------------------------------------
extern "C" void kernel_launch(void* const* d_in, const int* in_sizes, int n_in,
                              void* d_out, int out_size, void* d_ws, size_t ws_size,
                              hipStream_t stream) {
    (void)in_sizes; (void)n_in; (void)out_size; (void)ws_size;

    const float* x   = (const float*)d_in[0];
    const int*   ic1 = (const int*)d_in[1];
    const int*   ip1 = (const int*)d_in[2];
    const float* pW1 = (const float*)d_in[3];
    const float* pB1 = (const float*)d_in[4];
    const float* pG1 = (const float*)d_in[5];
    const float* pE1 = (const float*)d_in[6];
    const int*   ic2 = (const int*)d_in[7];
    const int*   ip2 = (const int*)d_in[8];
    const float* pW2 = (const float*)d_in[9];
    const float* pB2 = (const float*)d_in[10];
    const float* pG2 = (const float*)d_in[11];
    const float* pE2 = (const float*)d_in[12];
    const int*   ic3 = (const int*)d_in[13];
    const int*   ip3 = (const int*)d_in[14];
    const float* pW3 = (const float*)d_in[15];
    const float* pB3 = (const float*)d_in[16];
    const float* pG3 = (const float*)d_in[17];
    const float* pE3 = (const float*)d_in[18];
    const int*   ic4 = (const int*)d_in[19];
    const int*   ip4 = (const int*)d_in[20];
    const float* pW4 = (const float*)d_in[21];
    const float* pB4 = (const float*)d_in[22];
    const float* pG4 = (const float*)d_in[23];
    const float* pE4 = (const float*)d_in[24];
    const float* lw1 = (const float*)d_in[25];
    const float* lb1 = (const float*)d_in[26];
    const float* g5  = (const float*)d_in[27];
    const float* e5  = (const float*)d_in[28];
    const float* lw2 = (const float*)d_in[29];
    const float* lb2 = (const float*)d_in[30];

    char* ws = (char*)d_ws;
    size_t off = 0;
    auto alloc = [&](size_t bytes) -> char* {
        char* p = ws + off;
        off += (bytes + 511) & ~(size_t)511;
        return p;
    };

    float*  A0    = (float*) alloc((size_t)2 * 2048 * 2 * B * 4);      //   8.4 MB
    __bf16* act1  = (__bf16*)alloc((size_t)2 * 512 * B * 64 * 2);      //  33.5 MB
    char*   U     =          alloc((size_t)512 * B * 128 * 4);         //  67.1 MB (P1f, then convXf per-t)
    float*  P1f   = (float*)U;
    float*  convX = (float*)U;
    float*  Pf    = (float*) alloc((size_t)2 * 128 * B * 128 * 4);     //  33.5 MB
    __bf16* actS  = (__bf16*)alloc((size_t)2 * 128 * B * 128 * 2);     //  16.8 MB
    __bf16* Wr2   = (__bf16*)alloc((size_t)128 * 448 * 2);
    __bf16* Wr3   = (__bf16*)alloc((size_t)256 * 896 * 2);
    __bf16* Wr4   = (__bf16*)alloc((size_t)512 * 1792 * 2);
    __bf16* w1b   = (__bf16*)alloc((size_t)2048 * 4096 * 2);           //  16.8 MB
    __bf16* z     = (__bf16*)alloc((size_t)256 * 4096 * 2);            //   2.1 MB
    float*  o1    = (float*) alloc((size_t)2048 * B * 4);              //   2.1 MB
    float*  part  = (float*) alloc((size_t)2 * 128 * 4 * 1024 * 4);    //   4.2 MB
    float*  sc1 = (float*)alloc(2 * 64 * 4);
    float*  sh1 = (float*)alloc(2 * 64 * 4);
    float*  sc2 = (float*)alloc(2 * 128 * 4);
    float*  sh2 = (float*)alloc(2 * 128 * 4);
    float*  sc3 = (float*)alloc(2 * 256 * 4);
    float*  sh3 = (float*)alloc(2 * 256 * 4);
    float*  sc4 = (float*)alloc(2 * 512 * 4);
    float*  sh4 = (float*)alloc(2 * 512 * 4);
    float*  sc5 = (float*)alloc(2048 * 4);
    float*  sh5 = (float*)alloc(2048 * 4);

    // weight prep
    k_wr<<<(128 * 448 + 255) / 256, 256, 0, stream>>>(pW2, Wr2, 64, 128 * 448);
    k_wr<<<(256 * 896 + 255) / 256, 256, 0, stream>>>(pW3, Wr3, 128, 256 * 896);
    k_wr<<<(512 * 1792 + 255) / 256, 256, 0, stream>>>(pW4, Wr4, 256, 512 * 1792);
    k_cvt<<<(2048 * 4096) / 256, 256, 0, stream>>>(lw1, w1b, 2048 * 4096);

    // input transform
    k_transpose<<<256, 256, 0, stream>>>(x, A0);

    // layer 1 (fp32; single bf16 rounding in bnrelu1t)
    k_convpool1<<<2048, 256, 0, stream>>>(A0, P1f, pW1, pB1, ic1, ip1);
    k_stats1<<<2 * 64, 256, 0, stream>>>(P1f, pG1, pE1, sc1, sh1);
    k_bnrelu1t<<<2 * 512, 256, 0, stream>>>(P1f, sc1, sh1, act1);

    // layer 2: 64 -> 128, N 512 -> 128
    for (int t = 0; t < 2; t++) {
        k_conv_mfma<<<2 * 512, 256, 0, stream>>>(act1, convX, Wr2, ic2, 64, 128, 512, 6, t);
        k_poolstats<<<128 * 4, 256, 0, stream>>>(convX, Pf, pB2, ip2, part, 128, 512, 128, t);
    }
    k_finstats<<<2 * 128, 256, 0, stream>>>(part, pG2, pE2, sc2, sh2, 128, 128);
    k_bnrelu<<<(2 * 128 * B * 128) / 256, 256, 0, stream>>>(Pf, actS, sc2, sh2, 128, 2 * 128 * B * 128);

    // layer 3: 128 -> 256, N 128 -> 32
    for (int t = 0; t < 2; t++) {
        k_conv_mfma<<<4 * 128, 256, 0, stream>>>(actS, convX, Wr3, ic3, 128, 256, 128, 7, t);
        k_poolstats<<<32 * 4, 256, 0, stream>>>(convX, Pf, pB3, ip3, part, 256, 128, 32, t);
    }
    k_finstats<<<2 * 256, 256, 0, stream>>>(part, pG3, pE3, sc3, sh3, 256, 32);
    k_bnrelu<<<(2 * 32 * B * 256) / 256, 256, 0, stream>>>(Pf, actS, sc3, sh3, 256, 2 * 32 * B * 256);

    // layer 4: 256 -> 512, N 32 -> 8
    for (int t = 0; t < 2; t++) {
        k_conv_mfma<<<8 * 32, 256, 0, stream>>>(actS, convX, Wr4, ic4, 256, 512, 32, 8, t);
        k_poolstats<<<8 * 4, 256, 0, stream>>>(convX, Pf, pB4, ip4, part, 512, 32, 8, t);
    }
    k_finstats<<<2 * 512, 256, 0, stream>>>(part, pG4, pE4, sc4, sh4, 512, 8);

    // head
    k_zbuild<<<256, 256, 0, stream>>>(Pf, sc4, sh4, z);
    k_lin1<<<32, 256, 0, stream>>>(z, w1b, lb1, o1);
    k_stats5<<<2048, 256, 0, stream>>>(o1, g5, e5, sc5, sh5);
    k_final<<<256, 256, 0, stream>>>(o1, sc5, sh5, lw2, lb2, (float*)d_out);
}

// Round 5
// 811.767 us; speedup vs baseline: 11.4577x; 1.1304x over previous
//
#include <hip/hip_runtime.h>
#include <math.h>

#define B 256
#define KW 7

typedef __bf16 bf16x8 __attribute__((ext_vector_type(8)));
typedef __bf16 bf16x4 __attribute__((ext_vector_type(4)));
typedef float  f32x4  __attribute__((ext_vector_type(4)));

#define LDSW 36   // padded row stride (bf16 elems) for 32-elem MFMA weight rows

// ---------------------------------------------------------------------------
// helpers
// ---------------------------------------------------------------------------
__device__ __forceinline__ void block_reduce2(float& s, float& s2, float* lds) {
    for (int off = 32; off > 0; off >>= 1) {
        s  += __shfl_down(s,  off, 64);
        s2 += __shfl_down(s2, off, 64);
    }
    int wave = threadIdx.x >> 6;
    int lane = threadIdx.x & 63;
    if (lane == 0) { lds[wave * 2] = s; lds[wave * 2 + 1] = s2; }
    __syncthreads();
    if (threadIdx.x == 0) {
        s  = lds[0] + lds[2] + lds[4] + lds[6];
        s2 = lds[1] + lds[3] + lds[5] + lds[7];
    }
}

// ---------------------------------------------------------------------------
// x (B, 4, 2048) -> A0 [t][n][ci][b] fp32, LDS-tiled transpose
// ---------------------------------------------------------------------------
__global__ __launch_bounds__(256) void k_transpose(const float* __restrict__ x,
                                                   float* __restrict__ A0) {
    int bid = blockIdx.x;
    int nt  = bid & 63;
    int rem = bid >> 6;
    int ci  = rem & 1;
    int t   = rem >> 1;
    int n0  = nt * 32;
    __shared__ float lds[32][257];
    int tid = threadIdx.x;
    int nl  = tid & 31;
    int bq  = tid >> 5;
    int ch  = t * 2 + ci;
    for (int p = 0; p < 32; p++) {
        int b = bq + p * 8;
        lds[nl][b] = x[((size_t)b * 4 + ch) * 2048 + n0 + nl];
    }
    __syncthreads();
    for (int nl2 = 0; nl2 < 32; nl2++) {
        A0[(((size_t)t * 2048 + n0 + nl2) * 2 + ci) * B + tid] = lds[nl2][tid];
    }
}

// ---------------------------------------------------------------------------
// layer-1 fused conv+pool (fp32, Kt=14), output fp32 P1 [t][np][co][b]
// + per-block BN partial sums (s, s2 per 32 channels) -> part1c[bid][64]
// ---------------------------------------------------------------------------
__global__ __launch_bounds__(256) void k_convpool1(
    const float* __restrict__ act,      // [2][2048][2][256]
    float* __restrict__ P1,             // [2][512][64][256] fp32
    const float* __restrict__ w,        // [64][2][7]
    const float* __restrict__ bias,
    const int* __restrict__ idx_conv,   // [7][2048]
    const int* __restrict__ idx_pool,   // [7][512]
    float* __restrict__ part1c)         // [2048][64]  (32 s, 32 s2 per block)
{
    const int Kt = 14, C_out = 64, N_in = 2048, N_out = 512;
    int bid   = blockIdx.x;
    int cot   = bid & 1;
    int colid = bid >> 1;
    int t     = colid / N_out;
    int np    = colid - t * N_out;
    int co0   = cot << 5;

    __shared__ float lds_g[14 * 256];
    __shared__ float lds_w[14 * 33];
    __shared__ int   lds_idx[KW];

    int tid = threadIdx.x;
    int cog = tid >> 6;
    int bl  = tid & 63;

    float pmax[8][4];
    #pragma unroll
    for (int i = 0; i < 8; i++)
        #pragma unroll
        for (int j = 0; j < 4; j++) pmax[i][j] = -INFINITY;

    const float* actT = act + (size_t)t * N_in * 2 * B;

    for (int kp = 0; kp < KW; kp++) {
        int nc = idx_pool[kp * N_out + np];
        if (tid < KW) lds_idx[tid] = idx_conv[tid * N_in + nc];

        float acc[8][4];
        #pragma unroll
        for (int i = 0; i < 8; i++)
            #pragma unroll
            for (int j = 0; j < 4; j++) acc[i][j] = 0.f;

        __syncthreads();
        for (int e = tid; e < 32 * Kt; e += 256) {
            int kk = e % Kt;
            int co = e / Kt;
            lds_w[kk * 33 + co] = w[(size_t)(co0 + co) * Kt + kk];
        }
        for (int r = 0; r < Kt; r++) {
            int ci  = r / KW;
            int k   = r - ci * KW;
            int col = lds_idx[k];
            lds_g[r * 256 + tid] = actT[((size_t)col * 2 + ci) * B + tid];
        }
        __syncthreads();
        for (int kk = 0; kk < Kt; kk++) {
            float g0 = lds_g[kk * 256 + bl];
            float g1 = lds_g[kk * 256 + bl + 64];
            float g2 = lds_g[kk * 256 + bl + 128];
            float g3 = lds_g[kk * 256 + bl + 192];
            const float* wr = lds_w + kk * 33 + cog * 8;
            #pragma unroll
            for (int i = 0; i < 8; i++) {
                float wv = wr[i];
                acc[i][0] = fmaf(wv, g0, acc[i][0]);
                acc[i][1] = fmaf(wv, g1, acc[i][1]);
                acc[i][2] = fmaf(wv, g2, acc[i][2]);
                acc[i][3] = fmaf(wv, g3, acc[i][3]);
            }
        }
        #pragma unroll
        for (int i = 0; i < 8; i++)
            #pragma unroll
            for (int j = 0; j < 4; j++) pmax[i][j] = fmaxf(pmax[i][j], acc[i][j]);
    }

    float* outp = P1 + (((size_t)t * N_out + np) * C_out + co0) * B;
    float* pblk = part1c + (size_t)bid * 64;
    #pragma unroll
    for (int i = 0; i < 8; i++) {
        int co = cog * 8 + i;
        float bv = bias[co0 + co];
        float s = 0.f, s2 = 0.f;
        #pragma unroll
        for (int j = 0; j < 4; j++) {
            float val = pmax[i][j] + bv;
            outp[(size_t)co * B + bl + 64 * j] = val;
            s  += val;
            s2 += val * val;
        }
        // wave-level reduce over the 64 b-lanes
        for (int o = 32; o > 0; o >>= 1) {
            s  += __shfl_down(s,  o, 64);
            s2 += __shfl_down(s2, o, 64);
        }
        if ((tid & 63) == 0) {
            pblk[co]      = s;
            pblk[32 + co] = s2;
        }
    }
}

// ---------------------------------------------------------------------------
// BN1 stats from convpool1 partials: grid 2*64, block 256
// part1c layout: [(t*512+np)*2 + cot][64]
// ---------------------------------------------------------------------------
__global__ __launch_bounds__(256) void k_finstats1(
    const float* __restrict__ part1c,
    const float* __restrict__ gamma, const float* __restrict__ beta,
    float* __restrict__ scale, float* __restrict__ shift)
{
    int idx = blockIdx.x;            // t*64 + c
    int t = idx >> 6, c = idx & 63;
    int cot = c >> 5, cl = c & 31;
    float s = 0.f, s2 = 0.f;
    for (int np = threadIdx.x; np < 512; np += 256) {
        const float* pp = part1c + (size_t)((t * 512 + np) * 2 + cot) * 64;
        s  += pp[cl];
        s2 += pp[32 + cl];
    }
    __shared__ float lds[8];
    block_reduce2(s, s2, lds);
    if (threadIdx.x == 0) {
        float cnt  = 512.f * 256.f;
        float m    = s / cnt;
        float var  = s2 / cnt - m * m;
        float istd = rsqrtf(var + 1e-5f);
        float g    = gamma[c];
        scale[idx] = istd * g;
        shift[idx] = beta[c] - m * istd * g;
    }
}

// ---------------------------------------------------------------------------
// BN+relu + transpose: P1 fp32 [t][np][co][b] -> act1 bf16 [t][np][b][co]
// ---------------------------------------------------------------------------
__global__ __launch_bounds__(256) void k_bnrelu1t(
    const float* __restrict__ P1,
    const float* __restrict__ sc, const float* __restrict__ sh,
    __bf16* __restrict__ act1)
{
    int bid = blockIdx.x;
    int t = bid >> 9;
    int b = threadIdx.x;
    const float* src = P1 + (size_t)bid * 64 * B;
    __bf16* dst = act1 + (size_t)bid * B * 64 + (size_t)b * 64;
    const float* scp = sc + t * 64;
    const float* shp = sh + t * 64;
    __bf16 vals[64];
    #pragma unroll
    for (int co = 0; co < 64; co++) {
        float v = src[co * B + b];
        vals[co] = (__bf16)fmaxf(fmaf(v, scp[co], shp[co]), 0.f);
    }
    #pragma unroll
    for (int j = 0; j < 8; j++)
        *(bf16x8*)(dst + j * 8) = *(bf16x8*)&vals[j * 8];
}

// ---------------------------------------------------------------------------
// weight re-layout: w [C_out][C_in][7] fp32 -> wr [C_out][7][C_in] bf16
// ---------------------------------------------------------------------------
__global__ void k_wr(const float* __restrict__ w, __bf16* __restrict__ wr,
                     int C_in, int total) {
    int idx = blockIdx.x * 256 + threadIdx.x;
    if (idx >= total) return;
    int ci = idx % C_in;
    int r  = idx / C_in;
    int kt = r % 7;
    int co = r / 7;
    wr[idx] = (__bf16)w[((size_t)co * C_in + ci) * 7 + kt];
}

__global__ void k_cvt(const float* __restrict__ src, __bf16* __restrict__ dst, int total) {
    int idx = blockIdx.x * 256 + threadIdx.x;
    if (idx >= total) return;
    dst[idx] = (__bf16)src[idx];
}

// ---------------------------------------------------------------------------
// MFMA conv for one branch t: act [t][N][256][C_in] bf16 x wr [C_out][7][C_in]
//   -> convo [N][256][C_out] fp32
// ---------------------------------------------------------------------------
__global__ __launch_bounds__(256) void k_conv_mfma(
    const __bf16* __restrict__ act,
    float* __restrict__ convo,
    const __bf16* __restrict__ wr,
    const int* __restrict__ idx_conv,   // [7][N]
    int C_in, int C_out, int N, int ci_shift, int t)
{
    int nco = C_out >> 6;
    int bid = blockIdx.x;
    int cot = bid % nco;
    int n   = bid / nco;
    int co0 = cot * 64;
    int Kt  = C_in * KW;

    __shared__ __bf16 lds_w[64 * LDSW];

    int tid  = threadIdx.x;
    int wv   = tid >> 6;
    int lane = tid & 63;
    int quad = lane >> 4;
    int lid  = lane & 15;

    f32x4 acc[4][4];
    #pragma unroll
    for (int i = 0; i < 4; i++)
        #pragma unroll
        for (int j = 0; j < 4; j++) {
            acc[i][j][0] = 0.f; acc[i][j][1] = 0.f;
            acc[i][j][2] = 0.f; acc[i][j][3] = 0.f;
        }

    const __bf16* actT = act + (size_t)t * N * B * C_in;
    int wco  = tid >> 2;
    int wseg = tid & 3;
    const __bf16* wsrc = wr + (size_t)(co0 + wco) * Kt + wseg * 8;

    for (int k0 = 0; k0 < Kt; k0 += 32) {
        int kt  = k0 >> ci_shift;
        int ci0 = k0 & (C_in - 1);
        int col = idx_conv[kt * N + n];
        __syncthreads();
        *(bf16x8*)&lds_w[wco * LDSW + wseg * 8] = *(const bf16x8*)(wsrc + k0);
        __syncthreads();
        bf16x8 bfrag[4];
        const __bf16* gbase = actT + ((size_t)col * B + wv * 64 + lid) * C_in + ci0 + quad * 8;
        #pragma unroll
        for (int bt = 0; bt < 4; bt++)
            bfrag[bt] = *(const bf16x8*)(gbase + (size_t)bt * 16 * C_in);
        #pragma unroll
        for (int rt = 0; rt < 4; rt++) {
            bf16x8 afrag = *(const bf16x8*)&lds_w[(rt * 16 + lid) * LDSW + quad * 8];
            #pragma unroll
            for (int bt = 0; bt < 4; bt++)
                acc[rt][bt] = __builtin_amdgcn_mfma_f32_16x16x32_bf16(
                    afrag, bfrag[bt], acc[rt][bt], 0, 0, 0);
        }
    }

    float* outp = convo + (size_t)n * B * C_out;
    #pragma unroll
    for (int rt = 0; rt < 4; rt++)
        #pragma unroll
        for (int bt = 0; bt < 4; bt++) {
            int b  = wv * 64 + bt * 16 + lid;
            int co = co0 + rt * 16 + quad * 4;
            *(f32x4*)(outp + (size_t)b * C_out + co) = acc[rt][bt];
        }
}

// ---------------------------------------------------------------------------
// pool + bias + stats partials (fp32): convo [N][256][C] -> P [t][No][256][C] fp32
// ---------------------------------------------------------------------------
__global__ __launch_bounds__(256) void k_poolstats(
    const float* __restrict__ convo,
    float* __restrict__ P,
    const float* __restrict__ bias,
    const int* __restrict__ idx_pool,   // [7][No]
    float* __restrict__ part,
    int C, int N, int No, int t)
{
    int bid = blockIdx.x;
    int bg  = bid & 3;
    int np  = bid >> 2;
    int cols[7];
    #pragma unroll
    for (int k = 0; k < 7; k++) cols[k] = idx_pool[k * No + np];
    float* pout = P + ((size_t)(t * No + np) * B) * C;
    int tid = threadIdx.x;
    float s[2] = {0.f, 0.f}, s2[2] = {0.f, 0.f};
    int NC, c0, bstart, bstep, nb;
    if (C >= 256) { NC = C >> 8; c0 = tid;       bstart = 0;        bstep = 1; nb = 64; }
    else          { NC = 1;      c0 = tid & (C - 1); bstart = tid >> 7; bstep = 2; nb = 32; }
    for (int j = 0; j < NC; j++) {
        int c = c0 + j * 256;
        float bv = bias[c];
        for (int i = 0; i < nb; i++) {
            int b = bg * 64 + bstart + i * bstep;
            float m = -1e30f;
            #pragma unroll
            for (int k = 0; k < 7; k++) {
                float v = convo[((size_t)cols[k] * B + b) * C + c];
                m = fmaxf(m, v);
            }
            float val = m + bv;
            pout[(size_t)b * C + c] = val;
            s[j] += val; s2[j] += val * val;
        }
    }
    float* pp = part + (size_t)((t * No + np) * 4 + bg) * 1024;
    for (int j = 0; j < NC; j++) {
        pp[tid + j * 256]       = s[j];
        pp[512 + tid + j * 256] = s2[j];
    }
}

// ---------------------------------------------------------------------------
// finalize BN stats from poolstats partials (parallel, one block per (t,c))
// ---------------------------------------------------------------------------
__global__ __launch_bounds__(256) void k_finstats(
    const float* __restrict__ part,
    const float* __restrict__ gamma, const float* __restrict__ beta,
    float* __restrict__ scale, float* __restrict__ shift,
    int C, int No)
{
    int idx = blockIdx.x;            // t*C + c
    int t = idx / C, c = idx - t * C;
    int SMAX   = C < 256 ? 256 : C;
    int nslice = SMAX / C;
    int nblk   = No * 4;
    int total  = nblk * nslice;
    const float* pbase = part + (size_t)(t * No * 4) * 1024;
    float s = 0.f, s2 = 0.f;
    for (int e = threadIdx.x; e < total; e += 256) {
        int blk = e / nslice;
        int j   = e - blk * nslice;
        const float* pp = pbase + (size_t)blk * 1024;
        int sl = c + j * C;
        s  += pp[sl];
        s2 += pp[512 + sl];
    }
    __shared__ float lds[8];
    block_reduce2(s, s2, lds);
    if (threadIdx.x == 0) {
        float cnt  = (float)No * 256.f;
        float m    = s / cnt;
        float var  = s2 / cnt - m * m;
        float istd = rsqrtf(var + 1e-5f);
        float g    = gamma[c];
        scale[idx] = istd * g;
        shift[idx] = beta[c] - m * istd * g;
    }
}

// ---------------------------------------------------------------------------
// BN+relu: P fp32 [2][No][256][C] -> act bf16 same layout (single rounding)
// ---------------------------------------------------------------------------
__global__ void k_bnrelu(const float* __restrict__ P, __bf16* __restrict__ act,
                         const float* __restrict__ scale, const float* __restrict__ shift,
                         int C, int total)
{
    int idx = blockIdx.x * 256 + threadIdx.x;
    if (idx >= total) return;
    int c = idx & (C - 1);
    int t = idx >= (total >> 1) ? 1 : 0;
    int tc = t * C + c;
    float v = P[idx];
    act[idx] = (__bf16)fmaxf(fmaf(v, scale[tc], shift[tc]), 0.f);
}

// ---------------------------------------------------------------------------
// z [b][4096] bf16 from P4 fp32 [2][8][256][512]: BN+relu+avg in fp32, one rounding
// ---------------------------------------------------------------------------
__global__ __launch_bounds__(256) void k_zbuild(const float* __restrict__ P4,
                                                const float* __restrict__ sc4,
                                                const float* __restrict__ sh4,
                                                __bf16* __restrict__ z)
{
    int b = blockIdx.x;
    int tid = threadIdx.x;
    for (int j = 0; j < 2; j++) {
        int c = tid + j * 256;
        float s0 = sc4[c],       h0 = sh4[c];
        float s1 = sc4[512 + c], h1 = sh4[512 + c];
        #pragma unroll
        for (int np = 0; np < 8; np++) {
            float v0 = P4[(((size_t)0 * 8 + np) * B + b) * 512 + c];
            float v1 = P4[(((size_t)1 * 8 + np) * B + b) * 512 + c];
            float y0 = fmaxf(fmaf(v0, s0, h0), 0.f);
            float y1 = fmaxf(fmaf(v1, s1, h1), 0.f);
            z[(size_t)b * 4096 + c * 8 + np] = (__bf16)(0.5f * (y0 + y1));
        }
    }
}

// ---------------------------------------------------------------------------
// lin1 MFMA, K-split x8: partL[ks][h][b] = sum_{f in slice ks} w1b[h][f]*z[b][f]
// grid: 32 h-tiles x 8 k-slices = 256 blocks
// ---------------------------------------------------------------------------
__global__ __launch_bounds__(256) void k_lin1_part(
    const __bf16* __restrict__ zb,    // [256][4096]
    const __bf16* __restrict__ w1b,   // [2048][4096]
    float* __restrict__ partL)        // [8][2048][256]
{
    int ht = blockIdx.x >> 3;
    int ks = blockIdx.x & 7;
    int h0 = ht * 64;
    int f_beg = ks * 512, f_end = f_beg + 512;

    __shared__ __bf16 lds_w[64 * LDSW];

    int tid  = threadIdx.x;
    int wv   = tid >> 6;
    int lane = tid & 63;
    int quad = lane >> 4;
    int lid  = lane & 15;

    f32x4 acc[4][4];
    #pragma unroll
    for (int i = 0; i < 4; i++)
        #pragma unroll
        for (int j = 0; j < 4; j++) {
            acc[i][j][0] = 0.f; acc[i][j][1] = 0.f;
            acc[i][j][2] = 0.f; acc[i][j][3] = 0.f;
        }

    int wco  = tid >> 2;
    int wseg = tid & 3;
    const __bf16* wsrc = w1b + (size_t)(h0 + wco) * 4096 + wseg * 8;

    for (int f0 = f_beg; f0 < f_end; f0 += 32) {
        __syncthreads();
        *(bf16x8*)&lds_w[wco * LDSW + wseg * 8] = *(const bf16x8*)(wsrc + f0);
        __syncthreads();
        bf16x8 bfrag[4];
        const __bf16* gbase = zb + (size_t)(wv * 64 + lid) * 4096 + f0 + quad * 8;
        #pragma unroll
        for (int bt = 0; bt < 4; bt++)
            bfrag[bt] = *(const bf16x8*)(gbase + (size_t)bt * 16 * 4096);
        #pragma unroll
        for (int rt = 0; rt < 4; rt++) {
            bf16x8 afrag = *(const bf16x8*)&lds_w[(rt * 16 + lid) * LDSW + quad * 8];
            #pragma unroll
            for (int bt = 0; bt < 4; bt++)
                acc[rt][bt] = __builtin_amdgcn_mfma_f32_16x16x32_bf16(
                    afrag, bfrag[bt], acc[rt][bt], 0, 0, 0);
        }
    }
    float* outp = partL + (size_t)ks * 2048 * B;
    #pragma unroll
    for (int rt = 0; rt < 4; rt++)
        #pragma unroll
        for (int bt = 0; bt < 4; bt++) {
            int b = wv * 64 + bt * 16 + lid;
            int h = h0 + rt * 16 + quad * 4;
            #pragma unroll
            for (int r = 0; r < 4; r++)
                outp[(size_t)(h + r) * B + b] = acc[rt][bt][r];
        }
}

// ---------------------------------------------------------------------------
// reduce lin1 partials + bias -> o1, and BN5 stats, in one pass. grid 2048.
// ---------------------------------------------------------------------------
__global__ __launch_bounds__(256) void k_redstats5(
    const float* __restrict__ partL,  // [8][2048][256]
    const float* __restrict__ b1,
    const float* __restrict__ gamma5, const float* __restrict__ beta5,
    float* __restrict__ o1,           // [2048][256]
    float* __restrict__ scale5, float* __restrict__ shift5)
{
    int h = blockIdx.x;
    int b = threadIdx.x;
    float v = b1[h];
    #pragma unroll
    for (int s = 0; s < 8; s++)
        v += partL[((size_t)s * 2048 + h) * B + b];
    o1[(size_t)h * B + b] = v;
    float s1 = v, s2 = v * v;
    __shared__ float lds[8];
    block_reduce2(s1, s2, lds);
    if (threadIdx.x == 0) {
        float m    = s1 * (1.f / 256.f);
        float var  = s2 * (1.f / 256.f) - m * m;
        float istd = rsqrtf(var + 1e-5f);
        float g    = gamma5[h];
        scale5[h]  = istd * g;
        shift5[h]  = beta5[h] - m * istd * g;
    }
}

// ---------------------------------------------------------------------------
// final head
// ---------------------------------------------------------------------------
__global__ __launch_bounds__(256) void k_final(
    const float* __restrict__ o1,
    const float* __restrict__ scale5, const float* __restrict__ shift5,
    const float* __restrict__ w2, const float* __restrict__ b2,
    float* __restrict__ out)
{
    int b = blockIdx.x;
    int tid = threadIdx.x;
    float s0 = 0.f, s1 = 0.f, s2v = 0.f;
    for (int h = tid; h < 2048; h += 256) {
        float y = fmaxf(fmaf(o1[(size_t)h * B + b], scale5[h], shift5[h]), 0.f);
        s0  = fmaf(y, w2[h],        s0);
        s1  = fmaf(y, w2[2048 + h], s1);
        s2v = fmaf(y, w2[4096 + h], s2v);
    }
    for (int off = 32; off > 0; off >>= 1) {
        s0  += __shfl_down(s0,  off, 64);
        s1  += __shfl_down(s1,  off, 64);
        s2v += __shfl_down(s2v, off, 64);
    }
    __shared__ float lds[12];
    int wave = tid >> 6, lane = tid & 63;
    if (lane == 0) { lds[wave * 3] = s0; lds[wave * 3 + 1] = s1; lds[wave * 3 + 2] = s2v; }
    __syncthreads();
    if (tid == 0) {
        float o0 = lds[0] + lds[3] + lds[6] + lds[9]  + b2[0];
        float oa = lds[1] + lds[4] + lds[7] + lds[10] + b2[1];
        float ob = lds[2] + lds[5] + lds[8] + lds[11] + b2[2];
        float m   = fmaxf(o0, oa);
        float lse = m + logf(expf(o0 - m) + expf(oa - m));
        out[b * 3 + 0] = o0 - lse;
        out[b * 3 + 1] = oa - lse;
        out[b * 3 + 2] = ob;
    }
}

// ---------------------------------------------------------------------------
extern "C" void kernel_launch(void* const* d_in, const int* in_sizes, int n_in,
                              void* d_out, int out_size, void* d_ws, size_t ws_size,
                              hipStream_t stream) {
    (void)in_sizes; (void)n_in; (void)out_size; (void)ws_size;

    const float* x   = (const float*)d_in[0];
    const int*   ic1 = (const int*)d_in[1];
    const int*   ip1 = (const int*)d_in[2];
    const float* pW1 = (const float*)d_in[3];
    const float* pB1 = (const float*)d_in[4];
    const float* pG1 = (const float*)d_in[5];
    const float* pE1 = (const float*)d_in[6];
    const int*   ic2 = (const int*)d_in[7];
    const int*   ip2 = (const int*)d_in[8];
    const float* pW2 = (const float*)d_in[9];
    const float* pB2 = (const float*)d_in[10];
    const float* pG2 = (const float*)d_in[11];
    const float* pE2 = (const float*)d_in[12];
    const int*   ic3 = (const int*)d_in[13];
    const int*   ip3 = (const int*)d_in[14];
    const float* pW3 = (const float*)d_in[15];
    const float* pB3 = (const float*)d_in[16];
    const float* pG3 = (const float*)d_in[17];
    const float* pE3 = (const float*)d_in[18];
    const int*   ic4 = (const int*)d_in[19];
    const int*   ip4 = (const int*)d_in[20];
    const float* pW4 = (const float*)d_in[21];
    const float* pB4 = (const float*)d_in[22];
    const float* pG4 = (const float*)d_in[23];
    const float* pE4 = (const float*)d_in[24];
    const float* lw1 = (const float*)d_in[25];
    const float* lb1 = (const float*)d_in[26];
    const float* g5  = (const float*)d_in[27];
    const float* e5  = (const float*)d_in[28];
    const float* lw2 = (const float*)d_in[29];
    const float* lb2 = (const float*)d_in[30];

    char* ws = (char*)d_ws;
    size_t off = 0;
    auto alloc = [&](size_t bytes) -> char* {
        char* p = ws + off;
        off += (bytes + 511) & ~(size_t)511;
        return p;
    };

    float*  A0    = (float*) alloc((size_t)2 * 2048 * 2 * B * 4);      //   8.4 MB
    __bf16* act1  = (__bf16*)alloc((size_t)2 * 512 * B * 64 * 2);      //  33.5 MB
    char*   U     =          alloc((size_t)512 * B * 128 * 4);         //  67.1 MB
    float*  P1f   = (float*)U;            // layer-1 conv+pool out (dead after bnrelu1t)
    float*  convX = (float*)U;            // per-t dense conv out (dead after L4 poolstats)
    float*  partL = (float*)U;            // lin1 K-split partials [8][2048][256] (16.8 MB)
    float*  Pf    = (float*) alloc((size_t)2 * 128 * B * 128 * 4);     //  33.5 MB
    __bf16* actS  = (__bf16*)alloc((size_t)2 * 128 * B * 128 * 2);     //  16.8 MB
    __bf16* Wr2   = (__bf16*)alloc((size_t)128 * 448 * 2);
    __bf16* Wr3   = (__bf16*)alloc((size_t)256 * 896 * 2);
    __bf16* Wr4   = (__bf16*)alloc((size_t)512 * 1792 * 2);
    __bf16* w1b   = (__bf16*)alloc((size_t)2048 * 4096 * 2);           //  16.8 MB
    __bf16* z     = (__bf16*)alloc((size_t)256 * 4096 * 2);            //   2.1 MB
    float*  o1    = (float*) alloc((size_t)2048 * B * 4);              //   2.1 MB
    float*  part  = (float*) alloc((size_t)2 * 128 * 4 * 1024 * 4);    //   4.2 MB
    float*  part1c= (float*) alloc((size_t)2048 * 64 * 4);             //   0.5 MB
    float*  sc1 = (float*)alloc(2 * 64 * 4);
    float*  sh1 = (float*)alloc(2 * 64 * 4);
    float*  sc2 = (float*)alloc(2 * 128 * 4);
    float*  sh2 = (float*)alloc(2 * 128 * 4);
    float*  sc3 = (float*)alloc(2 * 256 * 4);
    float*  sh3 = (float*)alloc(2 * 256 * 4);
    float*  sc4 = (float*)alloc(2 * 512 * 4);
    float*  sh4 = (float*)alloc(2 * 512 * 4);
    float*  sc5 = (float*)alloc(2048 * 4);
    float*  sh5 = (float*)alloc(2048 * 4);

    // weight prep
    k_wr<<<(128 * 448 + 255) / 256, 256, 0, stream>>>(pW2, Wr2, 64, 128 * 448);
    k_wr<<<(256 * 896 + 255) / 256, 256, 0, stream>>>(pW3, Wr3, 128, 256 * 896);
    k_wr<<<(512 * 1792 + 255) / 256, 256, 0, stream>>>(pW4, Wr4, 256, 512 * 1792);
    k_cvt<<<(2048 * 4096) / 256, 256, 0, stream>>>(lw1, w1b, 2048 * 4096);

    // input transform
    k_transpose<<<256, 256, 0, stream>>>(x, A0);

    // layer 1 (fp32; BN partials fused into convpool1)
    k_convpool1<<<2048, 256, 0, stream>>>(A0, P1f, pW1, pB1, ic1, ip1, part1c);
    k_finstats1<<<2 * 64, 256, 0, stream>>>(part1c, pG1, pE1, sc1, sh1);
    k_bnrelu1t<<<2 * 512, 256, 0, stream>>>(P1f, sc1, sh1, act1);

    // layer 2: 64 -> 128, N 512 -> 128
    for (int t = 0; t < 2; t++) {
        k_conv_mfma<<<2 * 512, 256, 0, stream>>>(act1, convX, Wr2, ic2, 64, 128, 512, 6, t);
        k_poolstats<<<128 * 4, 256, 0, stream>>>(convX, Pf, pB2, ip2, part, 128, 512, 128, t);
    }
    k_finstats<<<2 * 128, 256, 0, stream>>>(part, pG2, pE2, sc2, sh2, 128, 128);
    k_bnrelu<<<(2 * 128 * B * 128) / 256, 256, 0, stream>>>(Pf, actS, sc2, sh2, 128, 2 * 128 * B * 128);

    // layer 3: 128 -> 256, N 128 -> 32
    for (int t = 0; t < 2; t++) {
        k_conv_mfma<<<4 * 128, 256, 0, stream>>>(actS, convX, Wr3, ic3, 128, 256, 128, 7, t);
        k_poolstats<<<32 * 4, 256, 0, stream>>>(convX, Pf, pB3, ip3, part, 256, 128, 32, t);
    }
    k_finstats<<<2 * 256, 256, 0, stream>>>(part, pG3, pE3, sc3, sh3, 256, 32);
    k_bnrelu<<<(2 * 32 * B * 256) / 256, 256, 0, stream>>>(Pf, actS, sc3, sh3, 256, 2 * 32 * B * 256);

    // layer 4: 256 -> 512, N 32 -> 8
    for (int t = 0; t < 2; t++) {
        k_conv_mfma<<<8 * 32, 256, 0, stream>>>(actS, convX, Wr4, ic4, 256, 512, 32, 8, t);
        k_poolstats<<<8 * 4, 256, 0, stream>>>(convX, Pf, pB4, ip4, part, 512, 32, 8, t);
    }
    k_finstats<<<2 * 512, 256, 0, stream>>>(part, pG4, pE4, sc4, sh4, 512, 8);

    // head: zbuild -> lin1 K-split (partials into dead convX region) -> fused reduce+stats
    k_zbuild<<<256, 256, 0, stream>>>(Pf, sc4, sh4, z);
    k_lin1_part<<<256, 256, 0, stream>>>(z, w1b, partL);
    k_redstats5<<<2048, 256, 0, stream>>>(partL, lb1, g5, e5, o1, sc5, sh5);
    k_final<<<256, 256, 0, stream>>>(o1, sc5, sh5, lw2, lb2, (float*)d_out);
}

// Round 6
// 763.432 us; speedup vs baseline: 12.1831x; 1.0633x over previous
//
#include <hip/hip_runtime.h>
#include <math.h>

#define B 256
#define KW 7

typedef __bf16 bf16x8 __attribute__((ext_vector_type(8)));
typedef __bf16 bf16x4 __attribute__((ext_vector_type(4)));
typedef float  f32x4  __attribute__((ext_vector_type(4)));

// ---------------------------------------------------------------------------
// helpers
// ---------------------------------------------------------------------------
__device__ __forceinline__ void block_reduce2(float& s, float& s2, float* lds) {
    for (int off = 32; off > 0; off >>= 1) {
        s  += __shfl_down(s,  off, 64);
        s2 += __shfl_down(s2, off, 64);
    }
    int wave = threadIdx.x >> 6;
    int lane = threadIdx.x & 63;
    if (lane == 0) { lds[wave * 2] = s; lds[wave * 2 + 1] = s2; }
    __syncthreads();
    if (threadIdx.x == 0) {
        s  = lds[0] + lds[2] + lds[4] + lds[6];
        s2 = lds[1] + lds[3] + lds[5] + lds[7];
    }
}

// ---------------------------------------------------------------------------
// x (B, 4, 2048) -> A0 [t][n][ci][b] fp32, LDS-tiled transpose
// ---------------------------------------------------------------------------
__global__ __launch_bounds__(256) void k_transpose(const float* __restrict__ x,
                                                   float* __restrict__ A0) {
    int bid = blockIdx.x;
    int nt  = bid & 63;
    int rem = bid >> 6;
    int ci  = rem & 1;
    int t   = rem >> 1;
    int n0  = nt * 32;
    __shared__ float lds[32][257];
    int tid = threadIdx.x;
    int nl  = tid & 31;
    int bq  = tid >> 5;
    int ch  = t * 2 + ci;
    for (int p = 0; p < 32; p++) {
        int b = bq + p * 8;
        lds[nl][b] = x[((size_t)b * 4 + ch) * 2048 + n0 + nl];
    }
    __syncthreads();
    for (int nl2 = 0; nl2 < 32; nl2++) {
        A0[(((size_t)t * 2048 + n0 + nl2) * 2 + ci) * B + tid] = lds[nl2][tid];
    }
}

// ---------------------------------------------------------------------------
// layer-1 fused conv+pool (fp32, Kt=14), output fp32 P1 [t][np][co][b]
// + per-block BN partial sums -> part1c[bid][64]
// ---------------------------------------------------------------------------
__global__ __launch_bounds__(256) void k_convpool1(
    const float* __restrict__ act,      // [2][2048][2][256]
    float* __restrict__ P1,             // [2][512][64][256] fp32
    const float* __restrict__ w,        // [64][2][7]
    const float* __restrict__ bias,
    const int* __restrict__ idx_conv,   // [7][2048]
    const int* __restrict__ idx_pool,   // [7][512]
    float* __restrict__ part1c)         // [2048][64]
{
    const int Kt = 14, C_out = 64, N_in = 2048, N_out = 512;
    int bid   = blockIdx.x;
    int cot   = bid & 1;
    int colid = bid >> 1;
    int t     = colid / N_out;
    int np    = colid - t * N_out;
    int co0   = cot << 5;

    __shared__ float lds_g[14 * 256];
    __shared__ float lds_w[14 * 33];
    __shared__ int   lds_idx[KW];

    int tid = threadIdx.x;
    int cog = tid >> 6;
    int bl  = tid & 63;

    float pmax[8][4];
    #pragma unroll
    for (int i = 0; i < 8; i++)
        #pragma unroll
        for (int j = 0; j < 4; j++) pmax[i][j] = -INFINITY;

    const float* actT = act + (size_t)t * N_in * 2 * B;

    for (int kp = 0; kp < KW; kp++) {
        int nc = idx_pool[kp * N_out + np];
        if (tid < KW) lds_idx[tid] = idx_conv[tid * N_in + nc];

        float acc[8][4];
        #pragma unroll
        for (int i = 0; i < 8; i++)
            #pragma unroll
            for (int j = 0; j < 4; j++) acc[i][j] = 0.f;

        __syncthreads();
        for (int e = tid; e < 32 * Kt; e += 256) {
            int kk = e % Kt;
            int co = e / Kt;
            lds_w[kk * 33 + co] = w[(size_t)(co0 + co) * Kt + kk];
        }
        for (int r = 0; r < Kt; r++) {
            int ci  = r / KW;
            int k   = r - ci * KW;
            int col = lds_idx[k];
            lds_g[r * 256 + tid] = actT[((size_t)col * 2 + ci) * B + tid];
        }
        __syncthreads();
        for (int kk = 0; kk < Kt; kk++) {
            float g0 = lds_g[kk * 256 + bl];
            float g1 = lds_g[kk * 256 + bl + 64];
            float g2 = lds_g[kk * 256 + bl + 128];
            float g3 = lds_g[kk * 256 + bl + 192];
            const float* wr = lds_w + kk * 33 + cog * 8;
            #pragma unroll
            for (int i = 0; i < 8; i++) {
                float wv = wr[i];
                acc[i][0] = fmaf(wv, g0, acc[i][0]);
                acc[i][1] = fmaf(wv, g1, acc[i][1]);
                acc[i][2] = fmaf(wv, g2, acc[i][2]);
                acc[i][3] = fmaf(wv, g3, acc[i][3]);
            }
        }
        #pragma unroll
        for (int i = 0; i < 8; i++)
            #pragma unroll
            for (int j = 0; j < 4; j++) pmax[i][j] = fmaxf(pmax[i][j], acc[i][j]);
    }

    float* outp = P1 + (((size_t)t * N_out + np) * C_out + co0) * B;
    float* pblk = part1c + (size_t)bid * 64;
    #pragma unroll
    for (int i = 0; i < 8; i++) {
        int co = cog * 8 + i;
        float bv = bias[co0 + co];
        float s = 0.f, s2 = 0.f;
        #pragma unroll
        for (int j = 0; j < 4; j++) {
            float val = pmax[i][j] + bv;
            outp[(size_t)co * B + bl + 64 * j] = val;
            s  += val;
            s2 += val * val;
        }
        for (int o = 32; o > 0; o >>= 1) {
            s  += __shfl_down(s,  o, 64);
            s2 += __shfl_down(s2, o, 64);
        }
        if ((tid & 63) == 0) {
            pblk[co]      = s;
            pblk[32 + co] = s2;
        }
    }
}

// ---------------------------------------------------------------------------
// BN1 stats from convpool1 partials
// ---------------------------------------------------------------------------
__global__ __launch_bounds__(256) void k_finstats1(
    const float* __restrict__ part1c,
    const float* __restrict__ gamma, const float* __restrict__ beta,
    float* __restrict__ scale, float* __restrict__ shift)
{
    int idx = blockIdx.x;            // t*64 + c
    int t = idx >> 6, c = idx & 63;
    int cot = c >> 5, cl = c & 31;
    float s = 0.f, s2 = 0.f;
    for (int np = threadIdx.x; np < 512; np += 256) {
        const float* pp = part1c + (size_t)((t * 512 + np) * 2 + cot) * 64;
        s  += pp[cl];
        s2 += pp[32 + cl];
    }
    __shared__ float lds[8];
    block_reduce2(s, s2, lds);
    if (threadIdx.x == 0) {
        float cnt  = 512.f * 256.f;
        float m    = s / cnt;
        float var  = s2 / cnt - m * m;
        float istd = rsqrtf(var + 1e-5f);
        float g    = gamma[c];
        scale[idx] = istd * g;
        shift[idx] = beta[c] - m * istd * g;
    }
}

// ---------------------------------------------------------------------------
// BN+relu + transpose: P1 fp32 [t][np][co][b] -> act1 bf16 [t][np][b][co]
// ---------------------------------------------------------------------------
__global__ __launch_bounds__(256) void k_bnrelu1t(
    const float* __restrict__ P1,
    const float* __restrict__ sc, const float* __restrict__ sh,
    __bf16* __restrict__ act1)
{
    int bid = blockIdx.x;
    int t = bid >> 9;
    int b = threadIdx.x;
    const float* src = P1 + (size_t)bid * 64 * B;
    __bf16* dst = act1 + (size_t)bid * B * 64 + (size_t)b * 64;
    const float* scp = sc + t * 64;
    const float* shp = sh + t * 64;
    __bf16 vals[64];
    #pragma unroll
    for (int co = 0; co < 64; co++) {
        float v = src[co * B + b];
        vals[co] = (__bf16)fmaxf(fmaf(v, scp[co], shp[co]), 0.f);
    }
    #pragma unroll
    for (int j = 0; j < 8; j++)
        *(bf16x8*)(dst + j * 8) = *(bf16x8*)&vals[j * 8];
}

// ---------------------------------------------------------------------------
// weight re-layout: w [C_out][C_in][7] fp32 -> wr [C_out][7][C_in] bf16
// ---------------------------------------------------------------------------
__global__ void k_wr(const float* __restrict__ w, __bf16* __restrict__ wr,
                     int C_in, int total) {
    int idx = blockIdx.x * 256 + threadIdx.x;
    if (idx >= total) return;
    int ci = idx % C_in;
    int r  = idx / C_in;
    int kt = r % 7;
    int co = r / 7;
    wr[idx] = (__bf16)w[((size_t)co * C_in + ci) * 7 + kt];
}

// vectorized fp32 -> bf16 convert, 8 elems/thread
__global__ void k_cvt8(const float* __restrict__ src, __bf16* __restrict__ dst, int total8) {
    int idx = blockIdx.x * 256 + threadIdx.x;
    if (idx >= total8) return;
    const f32x4* s4 = (const f32x4*)(src + (size_t)idx * 8);
    f32x4 a = s4[0], b = s4[1];
    bf16x8 v;
    v[0] = (__bf16)a[0]; v[1] = (__bf16)a[1]; v[2] = (__bf16)a[2]; v[3] = (__bf16)a[3];
    v[4] = (__bf16)b[0]; v[5] = (__bf16)b[1]; v[6] = (__bf16)b[2]; v[7] = (__bf16)b[3];
    *(bf16x8*)(dst + (size_t)idx * 8) = v;
}

// ---------------------------------------------------------------------------
// MFMA conv, barrier-free: A-fragments loaded directly from global (L2-hit).
// act [2][N][256][C_in] bf16 x wr [C_out][7][C_in] -> convo [nt][N][256][C_out] fp32
// grid: nco * N * nt ; block 256 (4 waves over b)
// ---------------------------------------------------------------------------
__global__ __launch_bounds__(256) void k_conv_mfma(
    const __bf16* __restrict__ act,
    float* __restrict__ convo,
    const __bf16* __restrict__ wr,
    const int* __restrict__ idx_conv,   // [7][N]
    int C_in, int C_out, int N, int ci_shift, int t0)
{
    int nco = C_out >> 6;
    int bid = blockIdx.x;
    int cot = bid % nco;
    int rem = bid / nco;
    int n    = rem % N;
    int tloc = rem / N;
    int t    = t0 + tloc;
    int co0  = cot * 64;
    int Kt   = C_in * KW;

    int tid  = threadIdx.x;
    int wv   = tid >> 6;
    int lane = tid & 63;
    int quad = lane >> 4;
    int lid  = lane & 15;

    f32x4 acc[4][4];
    #pragma unroll
    for (int i = 0; i < 4; i++)
        #pragma unroll
        for (int j = 0; j < 4; j++) {
            acc[i][j][0] = 0.f; acc[i][j][1] = 0.f;
            acc[i][j][2] = 0.f; acc[i][j][3] = 0.f;
        }

    const __bf16* actT = act + (size_t)t * N * B * C_in;
    // per-lane A base: row = co0 + rt*16 + lid, col = k0 + quad*8
    const __bf16* wbase = wr + (size_t)(co0 + lid) * Kt + quad * 8;

    for (int k0 = 0; k0 < Kt; k0 += 32) {
        int kt  = k0 >> ci_shift;
        int ci0 = k0 & (C_in - 1);
        int col = idx_conv[kt * N + n];

        bf16x8 afrag[4];
        #pragma unroll
        for (int rt = 0; rt < 4; rt++)
            afrag[rt] = *(const bf16x8*)(wbase + (size_t)rt * 16 * Kt + k0);

        bf16x8 bfrag[4];
        const __bf16* gbase = actT + ((size_t)col * B + wv * 64 + lid) * C_in + ci0 + quad * 8;
        #pragma unroll
        for (int bt = 0; bt < 4; bt++)
            bfrag[bt] = *(const bf16x8*)(gbase + (size_t)bt * 16 * C_in);

        #pragma unroll
        for (int rt = 0; rt < 4; rt++)
            #pragma unroll
            for (int bt = 0; bt < 4; bt++)
                acc[rt][bt] = __builtin_amdgcn_mfma_f32_16x16x32_bf16(
                    afrag[rt], bfrag[bt], acc[rt][bt], 0, 0, 0);
    }

    float* outp = convo + ((size_t)(tloc * N + n) * B) * C_out;
    #pragma unroll
    for (int rt = 0; rt < 4; rt++)
        #pragma unroll
        for (int bt = 0; bt < 4; bt++) {
            int b  = wv * 64 + bt * 16 + lid;
            int co = co0 + rt * 16 + quad * 4;
            *(f32x4*)(outp + (size_t)b * C_out + co) = acc[rt][bt];
        }
}

// ---------------------------------------------------------------------------
// pool + bias + stats partials (fp32): convo [nt][N][256][C] -> P [2][No][256][C]
// grid: nt * No * 4
// ---------------------------------------------------------------------------
__global__ __launch_bounds__(256) void k_poolstats(
    const float* __restrict__ convo,
    float* __restrict__ P,
    const float* __restrict__ bias,
    const int* __restrict__ idx_pool,   // [7][No]
    float* __restrict__ part,
    int C, int N, int No, int t0)
{
    int bid  = blockIdx.x;
    int bg   = bid & 3;
    int rem  = bid >> 2;
    int np   = rem % No;
    int tloc = rem / No;
    int t    = t0 + tloc;
    int cols[7];
    #pragma unroll
    for (int k = 0; k < 7; k++) cols[k] = idx_pool[k * No + np];
    const float* base = convo + (size_t)tloc * N * B * C;
    float* pout = P + ((size_t)(t * No + np) * B) * C;
    int tid = threadIdx.x;
    float s[2] = {0.f, 0.f}, s2[2] = {0.f, 0.f};
    int NC, c0, bstart, bstep, nb;
    if (C >= 256) { NC = C >> 8; c0 = tid;           bstart = 0;        bstep = 1; nb = 64; }
    else          { NC = 1;      c0 = tid & (C - 1); bstart = tid >> 7; bstep = 2; nb = 32; }
    for (int j = 0; j < NC; j++) {
        int c = c0 + j * 256;
        float bv = bias[c];
        for (int i = 0; i < nb; i++) {
            int b = bg * 64 + bstart + i * bstep;
            float m = -1e30f;
            #pragma unroll
            for (int k = 0; k < 7; k++) {
                float v = base[((size_t)cols[k] * B + b) * C + c];
                m = fmaxf(m, v);
            }
            float val = m + bv;
            pout[(size_t)b * C + c] = val;
            s[j] += val; s2[j] += val * val;
        }
    }
    float* pp = part + (size_t)((t * No + np) * 4 + bg) * 1024;
    for (int j = 0; j < NC; j++) {
        pp[tid + j * 256]       = s[j];
        pp[512 + tid + j * 256] = s2[j];
    }
}

// ---------------------------------------------------------------------------
// finalize BN stats from poolstats partials (one block per (t,c))
// ---------------------------------------------------------------------------
__global__ __launch_bounds__(256) void k_finstats(
    const float* __restrict__ part,
    const float* __restrict__ gamma, const float* __restrict__ beta,
    float* __restrict__ scale, float* __restrict__ shift,
    int C, int No)
{
    int idx = blockIdx.x;            // t*C + c
    int t = idx / C, c = idx - t * C;
    int SMAX   = C < 256 ? 256 : C;
    int nslice = SMAX / C;
    int nblk   = No * 4;
    int total  = nblk * nslice;
    const float* pbase = part + (size_t)(t * No * 4) * 1024;
    float s = 0.f, s2 = 0.f;
    for (int e = threadIdx.x; e < total; e += 256) {
        int blk = e / nslice;
        int j   = e - blk * nslice;
        const float* pp = pbase + (size_t)blk * 1024;
        int sl = c + j * C;
        s  += pp[sl];
        s2 += pp[512 + sl];
    }
    __shared__ float lds[8];
    block_reduce2(s, s2, lds);
    if (threadIdx.x == 0) {
        float cnt  = (float)No * 256.f;
        float m    = s / cnt;
        float var  = s2 / cnt - m * m;
        float istd = rsqrtf(var + 1e-5f);
        float g    = gamma[c];
        scale[idx] = istd * g;
        shift[idx] = beta[c] - m * istd * g;
    }
}

// ---------------------------------------------------------------------------
// BN+relu: P fp32 [2][No][256][C] -> act bf16 same layout (single rounding)
// ---------------------------------------------------------------------------
__global__ void k_bnrelu(const float* __restrict__ P, __bf16* __restrict__ act,
                         const float* __restrict__ scale, const float* __restrict__ shift,
                         int C, int total)
{
    int idx = blockIdx.x * 256 + threadIdx.x;
    if (idx >= total) return;
    int c = idx & (C - 1);
    int t = idx >= (total >> 1) ? 1 : 0;
    int tc = t * C + c;
    float v = P[idx];
    act[idx] = (__bf16)fmaxf(fmaf(v, scale[tc], shift[tc]), 0.f);
}

// ---------------------------------------------------------------------------
// z [b][4096] bf16 from P4 fp32 [2][8][256][512]: BN+relu+avg in fp32, one rounding
// ---------------------------------------------------------------------------
__global__ __launch_bounds__(256) void k_zbuild(const float* __restrict__ P4,
                                                const float* __restrict__ sc4,
                                                const float* __restrict__ sh4,
                                                __bf16* __restrict__ z)
{
    int b = blockIdx.x;
    int tid = threadIdx.x;
    for (int j = 0; j < 2; j++) {
        int c = tid + j * 256;
        float s0 = sc4[c],       h0 = sh4[c];
        float s1 = sc4[512 + c], h1 = sh4[512 + c];
        #pragma unroll
        for (int np = 0; np < 8; np++) {
            float v0 = P4[(((size_t)0 * 8 + np) * B + b) * 512 + c];
            float v1 = P4[(((size_t)1 * 8 + np) * B + b) * 512 + c];
            float y0 = fmaxf(fmaf(v0, s0, h0), 0.f);
            float y1 = fmaxf(fmaf(v1, s1, h1), 0.f);
            z[(size_t)b * 4096 + c * 8 + np] = (__bf16)(0.5f * (y0 + y1));
        }
    }
}

// ---------------------------------------------------------------------------
// lin1 MFMA, K-split x8, barrier-free (direct global A-fragments)
// grid: 32 h-tiles x 8 k-slices = 256 blocks
// ---------------------------------------------------------------------------
__global__ __launch_bounds__(256) void k_lin1_part(
    const __bf16* __restrict__ zb,    // [256][4096]
    const __bf16* __restrict__ w1b,   // [2048][4096]
    float* __restrict__ partL)        // [8][2048][256]
{
    int ht = blockIdx.x >> 3;
    int ks = blockIdx.x & 7;
    int h0 = ht * 64;
    int f_beg = ks * 512, f_end = f_beg + 512;

    int tid  = threadIdx.x;
    int wv   = tid >> 6;
    int lane = tid & 63;
    int quad = lane >> 4;
    int lid  = lane & 15;

    f32x4 acc[4][4];
    #pragma unroll
    for (int i = 0; i < 4; i++)
        #pragma unroll
        for (int j = 0; j < 4; j++) {
            acc[i][j][0] = 0.f; acc[i][j][1] = 0.f;
            acc[i][j][2] = 0.f; acc[i][j][3] = 0.f;
        }

    const __bf16* wbase = w1b + (size_t)(h0 + lid) * 4096 + quad * 8;
    const __bf16* zbase = zb + ((size_t)(wv * 64 + lid)) * 4096 + quad * 8;

    for (int f0 = f_beg; f0 < f_end; f0 += 32) {
        bf16x8 afrag[4];
        #pragma unroll
        for (int rt = 0; rt < 4; rt++)
            afrag[rt] = *(const bf16x8*)(wbase + (size_t)rt * 16 * 4096 + f0);
        bf16x8 bfrag[4];
        #pragma unroll
        for (int bt = 0; bt < 4; bt++)
            bfrag[bt] = *(const bf16x8*)(zbase + (size_t)bt * 16 * 4096 + f0);
        #pragma unroll
        for (int rt = 0; rt < 4; rt++)
            #pragma unroll
            for (int bt = 0; bt < 4; bt++)
                acc[rt][bt] = __builtin_amdgcn_mfma_f32_16x16x32_bf16(
                    afrag[rt], bfrag[bt], acc[rt][bt], 0, 0, 0);
    }
    float* outp = partL + (size_t)ks * 2048 * B;
    #pragma unroll
    for (int rt = 0; rt < 4; rt++)
        #pragma unroll
        for (int bt = 0; bt < 4; bt++) {
            int b = wv * 64 + bt * 16 + lid;
            int h = h0 + rt * 16 + quad * 4;
            #pragma unroll
            for (int r = 0; r < 4; r++)
                outp[(size_t)(h + r) * B + b] = acc[rt][bt][r];
        }
}

// ---------------------------------------------------------------------------
// reduce lin1 partials + bias -> o1, and BN5 stats, in one pass. grid 2048.
// ---------------------------------------------------------------------------
__global__ __launch_bounds__(256) void k_redstats5(
    const float* __restrict__ partL,  // [8][2048][256]
    const float* __restrict__ b1,
    const float* __restrict__ gamma5, const float* __restrict__ beta5,
    float* __restrict__ o1,           // [2048][256]
    float* __restrict__ scale5, float* __restrict__ shift5)
{
    int h = blockIdx.x;
    int b = threadIdx.x;
    float v = b1[h];
    #pragma unroll
    for (int s = 0; s < 8; s++)
        v += partL[((size_t)s * 2048 + h) * B + b];
    o1[(size_t)h * B + b] = v;
    float s1 = v, s2 = v * v;
    __shared__ float lds[8];
    block_reduce2(s1, s2, lds);
    if (threadIdx.x == 0) {
        float m    = s1 * (1.f / 256.f);
        float var  = s2 * (1.f / 256.f) - m * m;
        float istd = rsqrtf(var + 1e-5f);
        float g    = gamma5[h];
        scale5[h]  = istd * g;
        shift5[h]  = beta5[h] - m * istd * g;
    }
}

// ---------------------------------------------------------------------------
// final head
// ---------------------------------------------------------------------------
__global__ __launch_bounds__(256) void k_final(
    const float* __restrict__ o1,
    const float* __restrict__ scale5, const float* __restrict__ shift5,
    const float* __restrict__ w2, const float* __restrict__ b2,
    float* __restrict__ out)
{
    int b = blockIdx.x;
    int tid = threadIdx.x;
    float s0 = 0.f, s1 = 0.f, s2v = 0.f;
    for (int h = tid; h < 2048; h += 256) {
        float y = fmaxf(fmaf(o1[(size_t)h * B + b], scale5[h], shift5[h]), 0.f);
        s0  = fmaf(y, w2[h],        s0);
        s1  = fmaf(y, w2[2048 + h], s1);
        s2v = fmaf(y, w2[4096 + h], s2v);
    }
    for (int off = 32; off > 0; off >>= 1) {
        s0  += __shfl_down(s0,  off, 64);
        s1  += __shfl_down(s1,  off, 64);
        s2v += __shfl_down(s2v, off, 64);
    }
    __shared__ float lds[12];
    int wave = tid >> 6, lane = tid & 63;
    if (lane == 0) { lds[wave * 3] = s0; lds[wave * 3 + 1] = s1; lds[wave * 3 + 2] = s2v; }
    __syncthreads();
    if (tid == 0) {
        float o0 = lds[0] + lds[3] + lds[6] + lds[9]  + b2[0];
        float oa = lds[1] + lds[4] + lds[7] + lds[10] + b2[1];
        float ob = lds[2] + lds[5] + lds[8] + lds[11] + b2[2];
        float m   = fmaxf(o0, oa);
        float lse = m + logf(expf(o0 - m) + expf(oa - m));
        out[b * 3 + 0] = o0 - lse;
        out[b * 3 + 1] = oa - lse;
        out[b * 3 + 2] = ob;
    }
}

// ---------------------------------------------------------------------------
extern "C" void kernel_launch(void* const* d_in, const int* in_sizes, int n_in,
                              void* d_out, int out_size, void* d_ws, size_t ws_size,
                              hipStream_t stream) {
    (void)in_sizes; (void)n_in; (void)out_size; (void)ws_size;

    const float* x   = (const float*)d_in[0];
    const int*   ic1 = (const int*)d_in[1];
    const int*   ip1 = (const int*)d_in[2];
    const float* pW1 = (const float*)d_in[3];
    const float* pB1 = (const float*)d_in[4];
    const float* pG1 = (const float*)d_in[5];
    const float* pE1 = (const float*)d_in[6];
    const int*   ic2 = (const int*)d_in[7];
    const int*   ip2 = (const int*)d_in[8];
    const float* pW2 = (const float*)d_in[9];
    const float* pB2 = (const float*)d_in[10];
    const float* pG2 = (const float*)d_in[11];
    const float* pE2 = (const float*)d_in[12];
    const int*   ic3 = (const int*)d_in[13];
    const int*   ip3 = (const int*)d_in[14];
    const float* pW3 = (const float*)d_in[15];
    const float* pB3 = (const float*)d_in[16];
    const float* pG3 = (const float*)d_in[17];
    const float* pE3 = (const float*)d_in[18];
    const int*   ic4 = (const int*)d_in[19];
    const int*   ip4 = (const int*)d_in[20];
    const float* pW4 = (const float*)d_in[21];
    const float* pB4 = (const float*)d_in[22];
    const float* pG4 = (const float*)d_in[23];
    const float* pE4 = (const float*)d_in[24];
    const float* lw1 = (const float*)d_in[25];
    const float* lb1 = (const float*)d_in[26];
    const float* g5  = (const float*)d_in[27];
    const float* e5  = (const float*)d_in[28];
    const float* lw2 = (const float*)d_in[29];
    const float* lb2 = (const float*)d_in[30];

    char* ws = (char*)d_ws;
    size_t off = 0;
    auto alloc = [&](size_t bytes) -> char* {
        char* p = ws + off;
        off += (bytes + 511) & ~(size_t)511;
        return p;
    };

    float*  A0    = (float*) alloc((size_t)2 * 2048 * 2 * B * 4);      //   8.4 MB
    __bf16* act1  = (__bf16*)alloc((size_t)2 * 512 * B * 64 * 2);      //  33.5 MB
    char*   U     =          alloc((size_t)512 * B * 128 * 4);         //  67.1 MB
    float*  P1f   = (float*)U;            // layer-1 conv+pool out (dead after bnrelu1t)
    float*  convX = (float*)U;            // conv out: L2 per-t 67MB; L3 both-t 67MB; L4 both-t 33.5MB
    float*  partL = (float*)U;            // lin1 K-split partials [8][2048][256] (16.8 MB)
    float*  Pf    = (float*) alloc((size_t)2 * 128 * B * 128 * 4);     //  33.5 MB
    __bf16* actS  = (__bf16*)alloc((size_t)2 * 128 * B * 128 * 2);     //  16.8 MB
    __bf16* Wr2   = (__bf16*)alloc((size_t)128 * 448 * 2);
    __bf16* Wr3   = (__bf16*)alloc((size_t)256 * 896 * 2);
    __bf16* Wr4   = (__bf16*)alloc((size_t)512 * 1792 * 2);
    __bf16* w1b   = (__bf16*)alloc((size_t)2048 * 4096 * 2);           //  16.8 MB
    __bf16* z     = (__bf16*)alloc((size_t)256 * 4096 * 2);            //   2.1 MB
    float*  o1    = (float*) alloc((size_t)2048 * B * 4);              //   2.1 MB
    float*  part  = (float*) alloc((size_t)2 * 128 * 4 * 1024 * 4);    //   4.2 MB
    float*  part1c= (float*) alloc((size_t)2048 * 64 * 4);             //   0.5 MB
    float*  sc1 = (float*)alloc(2 * 64 * 4);
    float*  sh1 = (float*)alloc(2 * 64 * 4);
    float*  sc2 = (float*)alloc(2 * 128 * 4);
    float*  sh2 = (float*)alloc(2 * 128 * 4);
    float*  sc3 = (float*)alloc(2 * 256 * 4);
    float*  sh3 = (float*)alloc(2 * 256 * 4);
    float*  sc4 = (float*)alloc(2 * 512 * 4);
    float*  sh4 = (float*)alloc(2 * 512 * 4);
    float*  sc5 = (float*)alloc(2048 * 4);
    float*  sh5 = (float*)alloc(2048 * 4);

    // weight prep
    k_wr<<<(128 * 448 + 255) / 256, 256, 0, stream>>>(pW2, Wr2, 64, 128 * 448);
    k_wr<<<(256 * 896 + 255) / 256, 256, 0, stream>>>(pW3, Wr3, 128, 256 * 896);
    k_wr<<<(512 * 1792 + 255) / 256, 256, 0, stream>>>(pW4, Wr4, 256, 512 * 1792);
    k_cvt8<<<(2048 * 4096 / 8) / 256, 256, 0, stream>>>(lw1, w1b, 2048 * 4096 / 8);

    // input transform
    k_transpose<<<256, 256, 0, stream>>>(x, A0);

    // layer 1 (fp32; BN partials fused)
    k_convpool1<<<2048, 256, 0, stream>>>(A0, P1f, pW1, pB1, ic1, ip1, part1c);
    k_finstats1<<<2 * 64, 256, 0, stream>>>(part1c, pG1, pE1, sc1, sh1);
    k_bnrelu1t<<<2 * 512, 256, 0, stream>>>(P1f, sc1, sh1, act1);

    // layer 2: 64 -> 128, N 512 -> 128 (per-branch; convX holds one t at a time)
    for (int t = 0; t < 2; t++) {
        k_conv_mfma<<<2 * 512, 256, 0, stream>>>(act1, convX, Wr2, ic2, 64, 128, 512, 6, t);
        k_poolstats<<<128 * 4, 256, 0, stream>>>(convX, Pf, pB2, ip2, part, 128, 512, 128, t);
    }
    k_finstats<<<2 * 128, 256, 0, stream>>>(part, pG2, pE2, sc2, sh2, 128, 128);
    k_bnrelu<<<(2 * 128 * B * 128) / 256, 256, 0, stream>>>(Pf, actS, sc2, sh2, 128, 2 * 128 * B * 128);

    // layer 3: 128 -> 256, N 128 -> 32 (both branches in one launch; convX 67 MB)
    k_conv_mfma<<<4 * 128 * 2, 256, 0, stream>>>(actS, convX, Wr3, ic3, 128, 256, 128, 7, 0);
    k_poolstats<<<2 * 32 * 4, 256, 0, stream>>>(convX, Pf, pB3, ip3, part, 256, 128, 32, 0);
    k_finstats<<<2 * 256, 256, 0, stream>>>(part, pG3, pE3, sc3, sh3, 256, 32);
    k_bnrelu<<<(2 * 32 * B * 256) / 256, 256, 0, stream>>>(Pf, actS, sc3, sh3, 256, 2 * 32 * B * 256);

    // layer 4: 256 -> 512, N 32 -> 8 (both branches; convX 33.5 MB)
    k_conv_mfma<<<8 * 32 * 2, 256, 0, stream>>>(actS, convX, Wr4, ic4, 256, 512, 32, 8, 0);
    k_poolstats<<<2 * 8 * 4, 256, 0, stream>>>(convX, Pf, pB4, ip4, part, 512, 32, 8, 0);
    k_finstats<<<2 * 512, 256, 0, stream>>>(part, pG4, pE4, sc4, sh4, 512, 8);

    // head
    k_zbuild<<<256, 256, 0, stream>>>(Pf, sc4, sh4, z);
    k_lin1_part<<<256, 256, 0, stream>>>(z, w1b, partL);
    k_redstats5<<<2048, 256, 0, stream>>>(partL, lb1, g5, e5, o1, sc5, sh5);
    k_final<<<256, 256, 0, stream>>>(o1, sc5, sh5, lw2, lb2, (float*)d_out);
}

// Round 7
// 702.852 us; speedup vs baseline: 13.2332x; 1.0862x over previous
//
#include <hip/hip_runtime.h>
#include <math.h>

#define B 256
#define KW 7

typedef __bf16 bf16x8 __attribute__((ext_vector_type(8)));
typedef __bf16 bf16x4 __attribute__((ext_vector_type(4)));
typedef float  f32x4  __attribute__((ext_vector_type(4)));

// ---------------------------------------------------------------------------
// helpers
// ---------------------------------------------------------------------------
__device__ __forceinline__ void block_reduce2(float& s, float& s2, float* lds) {
    for (int off = 32; off > 0; off >>= 1) {
        s  += __shfl_down(s,  off, 64);
        s2 += __shfl_down(s2, off, 64);
    }
    int wave = threadIdx.x >> 6;
    int lane = threadIdx.x & 63;
    if (lane == 0) { lds[wave * 2] = s; lds[wave * 2 + 1] = s2; }
    __syncthreads();
    if (threadIdx.x == 0) {
        s  = lds[0] + lds[2] + lds[4] + lds[6];
        s2 = lds[1] + lds[3] + lds[5] + lds[7];
    }
}

// ---------------------------------------------------------------------------
// x (B, 4, 2048) -> A0 [t][n][ci][b] fp32, LDS-tiled transpose
// ---------------------------------------------------------------------------
__global__ __launch_bounds__(256) void k_transpose(const float* __restrict__ x,
                                                   float* __restrict__ A0) {
    int bid = blockIdx.x;
    int nt  = bid & 63;
    int rem = bid >> 6;
    int ci  = rem & 1;
    int t   = rem >> 1;
    int n0  = nt * 32;
    __shared__ float lds[32][257];
    int tid = threadIdx.x;
    int nl  = tid & 31;
    int bq  = tid >> 5;
    int ch  = t * 2 + ci;
    for (int p = 0; p < 32; p++) {
        int b = bq + p * 8;
        lds[nl][b] = x[((size_t)b * 4 + ch) * 2048 + n0 + nl];
    }
    __syncthreads();
    for (int nl2 = 0; nl2 < 32; nl2++) {
        A0[(((size_t)t * 2048 + n0 + nl2) * 2 + ci) * B + tid] = lds[nl2][tid];
    }
}

// ---------------------------------------------------------------------------
// layer-1 fused conv+pool (fp32, Kt=14), output fp32 P1 [t][np][co][b]
// + per-block BN partial sums -> part1c[bid][64]
// ---------------------------------------------------------------------------
__global__ __launch_bounds__(256) void k_convpool1(
    const float* __restrict__ act,      // [2][2048][2][256]
    float* __restrict__ P1,             // [2][512][64][256] fp32
    const float* __restrict__ w,        // [64][2][7]
    const float* __restrict__ bias,
    const int* __restrict__ idx_conv,   // [7][2048]
    const int* __restrict__ idx_pool,   // [7][512]
    float* __restrict__ part1c)         // [2048][64]
{
    const int Kt = 14, C_out = 64, N_in = 2048, N_out = 512;
    int bid   = blockIdx.x;
    int cot   = bid & 1;
    int colid = bid >> 1;
    int t     = colid / N_out;
    int np    = colid - t * N_out;
    int co0   = cot << 5;

    __shared__ float lds_g[14 * 256];
    __shared__ float lds_w[14 * 33];
    __shared__ int   lds_idx[KW];

    int tid = threadIdx.x;
    int cog = tid >> 6;
    int bl  = tid & 63;

    float pmax[8][4];
    #pragma unroll
    for (int i = 0; i < 8; i++)
        #pragma unroll
        for (int j = 0; j < 4; j++) pmax[i][j] = -INFINITY;

    const float* actT = act + (size_t)t * N_in * 2 * B;

    for (int kp = 0; kp < KW; kp++) {
        int nc = idx_pool[kp * N_out + np];
        if (tid < KW) lds_idx[tid] = idx_conv[tid * N_in + nc];

        float acc[8][4];
        #pragma unroll
        for (int i = 0; i < 8; i++)
            #pragma unroll
            for (int j = 0; j < 4; j++) acc[i][j] = 0.f;

        __syncthreads();
        for (int e = tid; e < 32 * Kt; e += 256) {
            int kk = e % Kt;
            int co = e / Kt;
            lds_w[kk * 33 + co] = w[(size_t)(co0 + co) * Kt + kk];
        }
        for (int r = 0; r < Kt; r++) {
            int ci  = r / KW;
            int k   = r - ci * KW;
            int col = lds_idx[k];
            lds_g[r * 256 + tid] = actT[((size_t)col * 2 + ci) * B + tid];
        }
        __syncthreads();
        for (int kk = 0; kk < Kt; kk++) {
            float g0 = lds_g[kk * 256 + bl];
            float g1 = lds_g[kk * 256 + bl + 64];
            float g2 = lds_g[kk * 256 + bl + 128];
            float g3 = lds_g[kk * 256 + bl + 192];
            const float* wr = lds_w + kk * 33 + cog * 8;
            #pragma unroll
            for (int i = 0; i < 8; i++) {
                float wv = wr[i];
                acc[i][0] = fmaf(wv, g0, acc[i][0]);
                acc[i][1] = fmaf(wv, g1, acc[i][1]);
                acc[i][2] = fmaf(wv, g2, acc[i][2]);
                acc[i][3] = fmaf(wv, g3, acc[i][3]);
            }
        }
        #pragma unroll
        for (int i = 0; i < 8; i++)
            #pragma unroll
            for (int j = 0; j < 4; j++) pmax[i][j] = fmaxf(pmax[i][j], acc[i][j]);
    }

    float* outp = P1 + (((size_t)t * N_out + np) * C_out + co0) * B;
    float* pblk = part1c + (size_t)bid * 64;
    #pragma unroll
    for (int i = 0; i < 8; i++) {
        int co = cog * 8 + i;
        float bv = bias[co0 + co];
        float s = 0.f, s2 = 0.f;
        #pragma unroll
        for (int j = 0; j < 4; j++) {
            float val = pmax[i][j] + bv;
            outp[(size_t)co * B + bl + 64 * j] = val;
            s  += val;
            s2 += val * val;
        }
        for (int o = 32; o > 0; o >>= 1) {
            s  += __shfl_down(s,  o, 64);
            s2 += __shfl_down(s2, o, 64);
        }
        if ((tid & 63) == 0) {
            pblk[co]      = s;
            pblk[32 + co] = s2;
        }
    }
}

// ---------------------------------------------------------------------------
// BN1 stats from convpool1 partials
// ---------------------------------------------------------------------------
__global__ __launch_bounds__(256) void k_finstats1(
    const float* __restrict__ part1c,
    const float* __restrict__ gamma, const float* __restrict__ beta,
    float* __restrict__ scale, float* __restrict__ shift)
{
    int idx = blockIdx.x;            // t*64 + c
    int t = idx >> 6, c = idx & 63;
    int cot = c >> 5, cl = c & 31;
    float s = 0.f, s2 = 0.f;
    for (int np = threadIdx.x; np < 512; np += 256) {
        const float* pp = part1c + (size_t)((t * 512 + np) * 2 + cot) * 64;
        s  += pp[cl];
        s2 += pp[32 + cl];
    }
    __shared__ float lds[8];
    block_reduce2(s, s2, lds);
    if (threadIdx.x == 0) {
        float cnt  = 512.f * 256.f;
        float m    = s / cnt;
        float var  = s2 / cnt - m * m;
        float istd = rsqrtf(var + 1e-5f);
        float g    = gamma[c];
        scale[idx] = istd * g;
        shift[idx] = beta[c] - m * istd * g;
    }
}

// ---------------------------------------------------------------------------
// BN+relu + transpose: P1 fp32 [t][np][co][b] -> act1 bf16 [t][np][b][co]
// ---------------------------------------------------------------------------
__global__ __launch_bounds__(256) void k_bnrelu1t(
    const float* __restrict__ P1,
    const float* __restrict__ sc, const float* __restrict__ sh,
    __bf16* __restrict__ act1)
{
    int bid = blockIdx.x;
    int t = bid >> 9;
    int b = threadIdx.x;
    const float* src = P1 + (size_t)bid * 64 * B;
    __bf16* dst = act1 + (size_t)bid * B * 64 + (size_t)b * 64;
    const float* scp = sc + t * 64;
    const float* shp = sh + t * 64;
    __bf16 vals[64];
    #pragma unroll
    for (int co = 0; co < 64; co++) {
        float v = src[co * B + b];
        vals[co] = (__bf16)fmaxf(fmaf(v, scp[co], shp[co]), 0.f);
    }
    #pragma unroll
    for (int j = 0; j < 8; j++)
        *(bf16x8*)(dst + j * 8) = *(bf16x8*)&vals[j * 8];
}

// ---------------------------------------------------------------------------
// weight re-layout: w [C_out][C_in][7] fp32 -> wr [C_out][7][C_in] bf16
// ---------------------------------------------------------------------------
__global__ void k_wr(const float* __restrict__ w, __bf16* __restrict__ wr,
                     int C_in, int total) {
    int idx = blockIdx.x * 256 + threadIdx.x;
    if (idx >= total) return;
    int ci = idx % C_in;
    int r  = idx / C_in;
    int kt = r % 7;
    int co = r / 7;
    wr[idx] = (__bf16)w[((size_t)co * C_in + ci) * 7 + kt];
}

// vectorized fp32 -> bf16 convert, 8 elems/thread
__global__ void k_cvt8(const float* __restrict__ src, __bf16* __restrict__ dst, int total8) {
    int idx = blockIdx.x * 256 + threadIdx.x;
    if (idx >= total8) return;
    const f32x4* s4 = (const f32x4*)(src + (size_t)idx * 8);
    f32x4 a = s4[0], b = s4[1];
    bf16x8 v;
    v[0] = (__bf16)a[0]; v[1] = (__bf16)a[1]; v[2] = (__bf16)a[2]; v[3] = (__bf16)a[3];
    v[4] = (__bf16)b[0]; v[5] = (__bf16)b[1]; v[6] = (__bf16)b[2]; v[7] = (__bf16)b[3];
    *(bf16x8*)(dst + (size_t)idx * 8) = v;
}

// ---------------------------------------------------------------------------
// MFMA conv, barrier-free, co-tile 128, bf16 output.
// act [2][N][256][C_in] bf16 x wr [C_out][7][C_in] -> convo [2][N][256][C_out] bf16
// grid: (C_out/128) * N * 2 ; block 256 (4 waves over b)
// ---------------------------------------------------------------------------
__global__ __launch_bounds__(256) void k_conv_mfma(
    const __bf16* __restrict__ act,
    __bf16* __restrict__ convo,
    const __bf16* __restrict__ wr,
    const int* __restrict__ idx_conv,   // [7][N]
    int C_in, int C_out, int N, int ci_shift)
{
    int nco = C_out >> 7;               // 128-wide co tiles
    int bid = blockIdx.x;
    int cot = bid % nco;
    int rem = bid / nco;
    int n   = rem % N;
    int t   = rem / N;
    int co0 = cot * 128;
    int Kt  = C_in * KW;

    int tid  = threadIdx.x;
    int wv   = tid >> 6;
    int lane = tid & 63;
    int quad = lane >> 4;
    int lid  = lane & 15;

    f32x4 acc[8][4];
    #pragma unroll
    for (int i = 0; i < 8; i++)
        #pragma unroll
        for (int j = 0; j < 4; j++) {
            acc[i][j][0] = 0.f; acc[i][j][1] = 0.f;
            acc[i][j][2] = 0.f; acc[i][j][3] = 0.f;
        }

    const __bf16* actT = act + (size_t)t * N * B * C_in;
    const __bf16* wbase = wr + (size_t)(co0 + lid) * Kt + quad * 8;

    for (int k0 = 0; k0 < Kt; k0 += 32) {
        int kt  = k0 >> ci_shift;
        int ci0 = k0 & (C_in - 1);
        int col = idx_conv[kt * N + n];

        bf16x8 bfrag[4];
        const __bf16* gbase = actT + ((size_t)col * B + wv * 64 + lid) * C_in + ci0 + quad * 8;
        #pragma unroll
        for (int bt = 0; bt < 4; bt++)
            bfrag[bt] = *(const bf16x8*)(gbase + (size_t)bt * 16 * C_in);

        #pragma unroll
        for (int rt = 0; rt < 8; rt++) {
            bf16x8 afrag = *(const bf16x8*)(wbase + (size_t)rt * 16 * Kt + k0);
            #pragma unroll
            for (int bt = 0; bt < 4; bt++)
                acc[rt][bt] = __builtin_amdgcn_mfma_f32_16x16x32_bf16(
                    afrag, bfrag[bt], acc[rt][bt], 0, 0, 0);
        }
    }

    __bf16* outp = convo + ((size_t)(t * N + n) * B) * C_out;
    #pragma unroll
    for (int rt = 0; rt < 8; rt++)
        #pragma unroll
        for (int bt = 0; bt < 4; bt++) {
            int b  = wv * 64 + bt * 16 + lid;
            int co = co0 + rt * 16 + quad * 4;
            bf16x4 v;
            v[0] = (__bf16)acc[rt][bt][0];
            v[1] = (__bf16)acc[rt][bt][1];
            v[2] = (__bf16)acc[rt][bt][2];
            v[3] = (__bf16)acc[rt][bt][3];
            *(bf16x4*)(outp + (size_t)b * C_out + co) = v;
        }
}

// ---------------------------------------------------------------------------
// pool + bias + stats partials: convo bf16 [2][N][256][C] -> P fp32 [2][No][256][C]
// grid: 2 * No * 4
// ---------------------------------------------------------------------------
__global__ __launch_bounds__(256) void k_poolstats(
    const __bf16* __restrict__ convo,
    float* __restrict__ P,
    const float* __restrict__ bias,
    const int* __restrict__ idx_pool,   // [7][No]
    float* __restrict__ part,
    int C, int N, int No)
{
    int bid  = blockIdx.x;
    int bg   = bid & 3;
    int rem  = bid >> 2;
    int np   = rem % No;
    int t    = rem / No;
    int cols[7];
    #pragma unroll
    for (int k = 0; k < 7; k++) cols[k] = idx_pool[k * No + np];
    const __bf16* base = convo + (size_t)t * N * B * C;
    float* pout = P + ((size_t)(t * No + np) * B) * C;
    int tid = threadIdx.x;
    float s[2] = {0.f, 0.f}, s2[2] = {0.f, 0.f};
    int NC, c0, bstart, bstep, nb;
    if (C >= 256) { NC = C >> 8; c0 = tid;           bstart = 0;        bstep = 1; nb = 64; }
    else          { NC = 1;      c0 = tid & (C - 1); bstart = tid >> 7; bstep = 2; nb = 32; }
    for (int j = 0; j < NC; j++) {
        int c = c0 + j * 256;
        float bv = bias[c];
        for (int i = 0; i < nb; i++) {
            int b = bg * 64 + bstart + i * bstep;
            float m = -1e30f;
            #pragma unroll
            for (int k = 0; k < 7; k++) {
                float v = (float)base[((size_t)cols[k] * B + b) * C + c];
                m = fmaxf(m, v);
            }
            float val = m + bv;
            pout[(size_t)b * C + c] = val;
            s[j] += val; s2[j] += val * val;
        }
    }
    float* pp = part + (size_t)((t * No + np) * 4 + bg) * 1024;
    for (int j = 0; j < NC; j++) {
        pp[tid + j * 256]       = s[j];
        pp[512 + tid + j * 256] = s2[j];
    }
}

// ---------------------------------------------------------------------------
// finalize BN stats from poolstats partials (one block per (t,c))
// ---------------------------------------------------------------------------
__global__ __launch_bounds__(256) void k_finstats(
    const float* __restrict__ part,
    const float* __restrict__ gamma, const float* __restrict__ beta,
    float* __restrict__ scale, float* __restrict__ shift,
    int C, int No)
{
    int idx = blockIdx.x;            // t*C + c
    int t = idx / C, c = idx - t * C;
    int SMAX   = C < 256 ? 256 : C;
    int nslice = SMAX / C;
    int nblk   = No * 4;
    int total  = nblk * nslice;
    const float* pbase = part + (size_t)(t * No * 4) * 1024;
    float s = 0.f, s2 = 0.f;
    for (int e = threadIdx.x; e < total; e += 256) {
        int blk = e / nslice;
        int j   = e - blk * nslice;
        const float* pp = pbase + (size_t)blk * 1024;
        int sl = c + j * C;
        s  += pp[sl];
        s2 += pp[512 + sl];
    }
    __shared__ float lds[8];
    block_reduce2(s, s2, lds);
    if (threadIdx.x == 0) {
        float cnt  = (float)No * 256.f;
        float m    = s / cnt;
        float var  = s2 / cnt - m * m;
        float istd = rsqrtf(var + 1e-5f);
        float g    = gamma[c];
        scale[idx] = istd * g;
        shift[idx] = beta[c] - m * istd * g;
    }
}

// ---------------------------------------------------------------------------
// BN+relu: P fp32 [2][No][256][C] -> act bf16 same layout
// ---------------------------------------------------------------------------
__global__ void k_bnrelu(const float* __restrict__ P, __bf16* __restrict__ act,
                         const float* __restrict__ scale, const float* __restrict__ shift,
                         int C, int total)
{
    int idx = blockIdx.x * 256 + threadIdx.x;
    if (idx >= total) return;
    int c = idx & (C - 1);
    int t = idx >= (total >> 1) ? 1 : 0;
    int tc = t * C + c;
    float v = P[idx];
    act[idx] = (__bf16)fmaxf(fmaf(v, scale[tc], shift[tc]), 0.f);
}

// ---------------------------------------------------------------------------
// z [b][4096] bf16 from P4 fp32 [2][8][256][512]: BN+relu+avg in fp32, one rounding
// ---------------------------------------------------------------------------
__global__ __launch_bounds__(256) void k_zbuild(const float* __restrict__ P4,
                                                const float* __restrict__ sc4,
                                                const float* __restrict__ sh4,
                                                __bf16* __restrict__ z)
{
    int b = blockIdx.x;
    int tid = threadIdx.x;
    for (int j = 0; j < 2; j++) {
        int c = tid + j * 256;
        float s0 = sc4[c],       h0 = sh4[c];
        float s1 = sc4[512 + c], h1 = sh4[512 + c];
        #pragma unroll
        for (int np = 0; np < 8; np++) {
            float v0 = P4[(((size_t)0 * 8 + np) * B + b) * 512 + c];
            float v1 = P4[(((size_t)1 * 8 + np) * B + b) * 512 + c];
            float y0 = fmaxf(fmaf(v0, s0, h0), 0.f);
            float y1 = fmaxf(fmaf(v1, s1, h1), 0.f);
            z[(size_t)b * 4096 + c * 8 + np] = (__bf16)(0.5f * (y0 + y1));
        }
    }
}

// ---------------------------------------------------------------------------
// lin1 MFMA, K-split x8, barrier-free
// ---------------------------------------------------------------------------
__global__ __launch_bounds__(256) void k_lin1_part(
    const __bf16* __restrict__ zb,    // [256][4096]
    const __bf16* __restrict__ w1b,   // [2048][4096]
    float* __restrict__ partL)        // [8][2048][256]
{
    int ht = blockIdx.x >> 3;
    int ks = blockIdx.x & 7;
    int h0 = ht * 64;
    int f_beg = ks * 512, f_end = f_beg + 512;

    int tid  = threadIdx.x;
    int wv   = tid >> 6;
    int lane = tid & 63;
    int quad = lane >> 4;
    int lid  = lane & 15;

    f32x4 acc[4][4];
    #pragma unroll
    for (int i = 0; i < 4; i++)
        #pragma unroll
        for (int j = 0; j < 4; j++) {
            acc[i][j][0] = 0.f; acc[i][j][1] = 0.f;
            acc[i][j][2] = 0.f; acc[i][j][3] = 0.f;
        }

    const __bf16* wbase = w1b + (size_t)(h0 + lid) * 4096 + quad * 8;
    const __bf16* zbase = zb + ((size_t)(wv * 64 + lid)) * 4096 + quad * 8;

    for (int f0 = f_beg; f0 < f_end; f0 += 32) {
        bf16x8 afrag[4];
        #pragma unroll
        for (int rt = 0; rt < 4; rt++)
            afrag[rt] = *(const bf16x8*)(wbase + (size_t)rt * 16 * 4096 + f0);
        bf16x8 bfrag[4];
        #pragma unroll
        for (int bt = 0; bt < 4; bt++)
            bfrag[bt] = *(const bf16x8*)(zbase + (size_t)bt * 16 * 4096 + f0);
        #pragma unroll
        for (int rt = 0; rt < 4; rt++)
            #pragma unroll
            for (int bt = 0; bt < 4; bt++)
                acc[rt][bt] = __builtin_amdgcn_mfma_f32_16x16x32_bf16(
                    afrag[rt], bfrag[bt], acc[rt][bt], 0, 0, 0);
    }
    float* outp = partL + (size_t)ks * 2048 * B;
    #pragma unroll
    for (int rt = 0; rt < 4; rt++)
        #pragma unroll
        for (int bt = 0; bt < 4; bt++) {
            int b = wv * 64 + bt * 16 + lid;
            int h = h0 + rt * 16 + quad * 4;
            #pragma unroll
            for (int r = 0; r < 4; r++)
                outp[(size_t)(h + r) * B + b] = acc[rt][bt][r];
        }
}

// ---------------------------------------------------------------------------
// reduce lin1 partials + bias -> o1, and BN5 stats, in one pass. grid 2048.
// ---------------------------------------------------------------------------
__global__ __launch_bounds__(256) void k_redstats5(
    const float* __restrict__ partL,  // [8][2048][256]
    const float* __restrict__ b1,
    const float* __restrict__ gamma5, const float* __restrict__ beta5,
    float* __restrict__ o1,           // [2048][256]
    float* __restrict__ scale5, float* __restrict__ shift5)
{
    int h = blockIdx.x;
    int b = threadIdx.x;
    float v = b1[h];
    #pragma unroll
    for (int s = 0; s < 8; s++)
        v += partL[((size_t)s * 2048 + h) * B + b];
    o1[(size_t)h * B + b] = v;
    float s1 = v, s2 = v * v;
    __shared__ float lds[8];
    block_reduce2(s1, s2, lds);
    if (threadIdx.x == 0) {
        float m    = s1 * (1.f / 256.f);
        float var  = s2 * (1.f / 256.f) - m * m;
        float istd = rsqrtf(var + 1e-5f);
        float g    = gamma5[h];
        scale5[h]  = istd * g;
        shift5[h]  = beta5[h] - m * istd * g;
    }
}

// ---------------------------------------------------------------------------
// final head
// ---------------------------------------------------------------------------
__global__ __launch_bounds__(256) void k_final(
    const float* __restrict__ o1,
    const float* __restrict__ scale5, const float* __restrict__ shift5,
    const float* __restrict__ w2, const float* __restrict__ b2,
    float* __restrict__ out)
{
    int b = blockIdx.x;
    int tid = threadIdx.x;
    float s0 = 0.f, s1 = 0.f, s2v = 0.f;
    for (int h = tid; h < 2048; h += 256) {
        float y = fmaxf(fmaf(o1[(size_t)h * B + b], scale5[h], shift5[h]), 0.f);
        s0  = fmaf(y, w2[h],        s0);
        s1  = fmaf(y, w2[2048 + h], s1);
        s2v = fmaf(y, w2[4096 + h], s2v);
    }
    for (int off = 32; off > 0; off >>= 1) {
        s0  += __shfl_down(s0,  off, 64);
        s1  += __shfl_down(s1,  off, 64);
        s2v += __shfl_down(s2v, off, 64);
    }
    __shared__ float lds[12];
    int wave = tid >> 6, lane = tid & 63;
    if (lane == 0) { lds[wave * 3] = s0; lds[wave * 3 + 1] = s1; lds[wave * 3 + 2] = s2v; }
    __syncthreads();
    if (tid == 0) {
        float o0 = lds[0] + lds[3] + lds[6] + lds[9]  + b2[0];
        float oa = lds[1] + lds[4] + lds[7] + lds[10] + b2[1];
        float ob = lds[2] + lds[5] + lds[8] + lds[11] + b2[2];
        float m   = fmaxf(o0, oa);
        float lse = m + logf(expf(o0 - m) + expf(oa - m));
        out[b * 3 + 0] = o0 - lse;
        out[b * 3 + 1] = oa - lse;
        out[b * 3 + 2] = ob;
    }
}

// ---------------------------------------------------------------------------
extern "C" void kernel_launch(void* const* d_in, const int* in_sizes, int n_in,
                              void* d_out, int out_size, void* d_ws, size_t ws_size,
                              hipStream_t stream) {
    (void)in_sizes; (void)n_in; (void)out_size; (void)ws_size;

    const float* x   = (const float*)d_in[0];
    const int*   ic1 = (const int*)d_in[1];
    const int*   ip1 = (const int*)d_in[2];
    const float* pW1 = (const float*)d_in[3];
    const float* pB1 = (const float*)d_in[4];
    const float* pG1 = (const float*)d_in[5];
    const float* pE1 = (const float*)d_in[6];
    const int*   ic2 = (const int*)d_in[7];
    const int*   ip2 = (const int*)d_in[8];
    const float* pW2 = (const float*)d_in[9];
    const float* pB2 = (const float*)d_in[10];
    const float* pG2 = (const float*)d_in[11];
    const float* pE2 = (const float*)d_in[12];
    const int*   ic3 = (const int*)d_in[13];
    const int*   ip3 = (const int*)d_in[14];
    const float* pW3 = (const float*)d_in[15];
    const float* pB3 = (const float*)d_in[16];
    const float* pG3 = (const float*)d_in[17];
    const float* pE3 = (const float*)d_in[18];
    const int*   ic4 = (const int*)d_in[19];
    const int*   ip4 = (const int*)d_in[20];
    const float* pW4 = (const float*)d_in[21];
    const float* pB4 = (const float*)d_in[22];
    const float* pG4 = (const float*)d_in[23];
    const float* pE4 = (const float*)d_in[24];
    const float* lw1 = (const float*)d_in[25];
    const float* lb1 = (const float*)d_in[26];
    const float* g5  = (const float*)d_in[27];
    const float* e5  = (const float*)d_in[28];
    const float* lw2 = (const float*)d_in[29];
    const float* lb2 = (const float*)d_in[30];

    char* ws = (char*)d_ws;
    size_t off = 0;
    auto alloc = [&](size_t bytes) -> char* {
        char* p = ws + off;
        off += (bytes + 511) & ~(size_t)511;
        return p;
    };

    float*  A0    = (float*) alloc((size_t)2 * 2048 * 2 * B * 4);      //   8.4 MB
    __bf16* act1  = (__bf16*)alloc((size_t)2 * 512 * B * 64 * 2);      //  33.5 MB
    char*   U     =          alloc((size_t)512 * B * 128 * 4);         //  67.1 MB
    float*  P1f   = (float*)U;            // layer-1 conv+pool out (dead after bnrelu1t)
    __bf16* convX = (__bf16*)U;           // bf16 conv out: L2 67MB, L3 33.5MB, L4 8.4MB (both t)
    float*  partL = (float*)U;            // lin1 K-split partials [8][2048][256] (16.8 MB)
    float*  Pf    = (float*) alloc((size_t)2 * 128 * B * 128 * 4);     //  33.5 MB
    __bf16* actS  = (__bf16*)alloc((size_t)2 * 128 * B * 128 * 2);     //  16.8 MB
    __bf16* Wr2   = (__bf16*)alloc((size_t)128 * 448 * 2);
    __bf16* Wr3   = (__bf16*)alloc((size_t)256 * 896 * 2);
    __bf16* Wr4   = (__bf16*)alloc((size_t)512 * 1792 * 2);
    __bf16* w1b   = (__bf16*)alloc((size_t)2048 * 4096 * 2);           //  16.8 MB
    __bf16* z     = (__bf16*)alloc((size_t)256 * 4096 * 2);            //   2.1 MB
    float*  o1    = (float*) alloc((size_t)2048 * B * 4);              //   2.1 MB
    float*  part  = (float*) alloc((size_t)2 * 128 * 4 * 1024 * 4);    //   4.2 MB
    float*  part1c= (float*) alloc((size_t)2048 * 64 * 4);             //   0.5 MB
    float*  sc1 = (float*)alloc(2 * 64 * 4);
    float*  sh1 = (float*)alloc(2 * 64 * 4);
    float*  sc2 = (float*)alloc(2 * 128 * 4);
    float*  sh2 = (float*)alloc(2 * 128 * 4);
    float*  sc3 = (float*)alloc(2 * 256 * 4);
    float*  sh3 = (float*)alloc(2 * 256 * 4);
    float*  sc4 = (float*)alloc(2 * 512 * 4);
    float*  sh4 = (float*)alloc(2 * 512 * 4);
    float*  sc5 = (float*)alloc(2048 * 4);
    float*  sh5 = (float*)alloc(2048 * 4);

    // weight prep
    k_wr<<<(128 * 448 + 255) / 256, 256, 0, stream>>>(pW2, Wr2, 64, 128 * 448);
    k_wr<<<(256 * 896 + 255) / 256, 256, 0, stream>>>(pW3, Wr3, 128, 256 * 896);
    k_wr<<<(512 * 1792 + 255) / 256, 256, 0, stream>>>(pW4, Wr4, 256, 512 * 1792);
    k_cvt8<<<(2048 * 4096 / 8) / 256, 256, 0, stream>>>(lw1, w1b, 2048 * 4096 / 8);

    // input transform
    k_transpose<<<256, 256, 0, stream>>>(x, A0);

    // layer 1 (fp32; BN partials fused)
    k_convpool1<<<2048, 256, 0, stream>>>(A0, P1f, pW1, pB1, ic1, ip1, part1c);
    k_finstats1<<<2 * 64, 256, 0, stream>>>(part1c, pG1, pE1, sc1, sh1);
    k_bnrelu1t<<<2 * 512, 256, 0, stream>>>(P1f, sc1, sh1, act1);

    // layer 2: 64 -> 128, N 512 -> 128 (both branches, bf16 convX 67 MB)
    k_conv_mfma<<<1 * 512 * 2, 256, 0, stream>>>(act1, convX, Wr2, ic2, 64, 128, 512, 6);
    k_poolstats<<<2 * 128 * 4, 256, 0, stream>>>(convX, Pf, pB2, ip2, part, 128, 512, 128);
    k_finstats<<<2 * 128, 256, 0, stream>>>(part, pG2, pE2, sc2, sh2, 128, 128);
    k_bnrelu<<<(2 * 128 * B * 128) / 256, 256, 0, stream>>>(Pf, actS, sc2, sh2, 128, 2 * 128 * B * 128);

    // layer 3: 128 -> 256, N 128 -> 32 (bf16 convX 33.5 MB)
    k_conv_mfma<<<2 * 128 * 2, 256, 0, stream>>>(actS, convX, Wr3, ic3, 128, 256, 128, 7);
    k_poolstats<<<2 * 32 * 4, 256, 0, stream>>>(convX, Pf, pB3, ip3, part, 256, 128, 32);
    k_finstats<<<2 * 256, 256, 0, stream>>>(part, pG3, pE3, sc3, sh3, 256, 32);
    k_bnrelu<<<(2 * 32 * B * 256) / 256, 256, 0, stream>>>(Pf, actS, sc3, sh3, 256, 2 * 32 * B * 256);

    // layer 4: 256 -> 512, N 32 -> 8 (bf16 convX 8.4 MB)
    k_conv_mfma<<<4 * 32 * 2, 256, 0, stream>>>(actS, convX, Wr4, ic4, 256, 512, 32, 8);
    k_poolstats<<<2 * 8 * 4, 256, 0, stream>>>(convX, Pf, pB4, ip4, part, 512, 32, 8);
    k_finstats<<<2 * 512, 256, 0, stream>>>(part, pG4, pE4, sc4, sh4, 512, 8);

    // head
    k_zbuild<<<256, 256, 0, stream>>>(Pf, sc4, sh4, z);
    k_lin1_part<<<256, 256, 0, stream>>>(z, w1b, partL);
    k_redstats5<<<2048, 256, 0, stream>>>(partL, lb1, g5, e5, o1, sc5, sh5);
    k_final<<<256, 256, 0, stream>>>(o1, sc5, sh5, lw2, lb2, (float*)d_out);
}